// Round 16
// baseline (292.429 us; speedup 1.0000x reference)
//
#include <hip/hip_runtime.h>
#include <hip/hip_bf16.h>
#include <cstdint>

#define DI __device__ __forceinline__

typedef short bf16x8 __attribute__((ext_vector_type(8)));
typedef float f32x4 __attribute__((ext_vector_type(4)));
typedef unsigned short u16;
typedef unsigned short u16x8 __attribute__((ext_vector_type(8)));

static constexpr int NV = 10, NE = 90, TT = 64;
static constexpr int R1 = 20480;   // 32*10*64 node rows
static constexpr int R2 = 184320;  // 32*90*64 edge rows
static constexpr float INV_R1 = 1.f / 20480.f;
static constexpr float INV_R2 = 1.f / 184320.f;

DI float bf2f(u16 u) { union { unsigned int i; float f; } x; x.i = ((unsigned int)u) << 16; return x.f; }
DI u16 f2bf(float f) { unsigned int u = __float_as_uint(f); return (u16)((u + 0x7FFF + ((u >> 16) & 1)) >> 16); }
DI float elu(float v) { return v > 0.f ? v : __expf(v) - 1.f; }

#define GLL(srcp, dstp) __builtin_amdgcn_global_load_lds( \
    (const __attribute__((address_space(1))) unsigned int*)(srcp), \
    (__attribute__((address_space(3))) unsigned int*)(dstp), 16, 0, 0)

// ============================================================================
// 128-tile weight packing (mlp1-fc2 gemm, r8-verified)
// ============================================================================
__global__ __launch_bounds__(256) void pack128(const float* __restrict__ s,
                                               u16* __restrict__ d) {
    int tid = threadIdx.x;
    int bn = blockIdx.x >> 3, kt = blockIdx.x & 7;
#pragma unroll
    for (int p = 0; p < 2; ++p) {
        int n = bn * 128 + p * 64 + (tid >> 2);
        int k = kt * 32 + (tid & 3) * 8;
        u16x8 pk;
#pragma unroll
        for (int e = 0; e < 8; ++e) pk[e] = f2bf(s[(size_t)(k + e) * 256 + n]);
        *(u16x8*)(d + ((size_t)((bn * 8 + kt) * 2 + p)) * 2048 + (size_t)tid * 8) = pk;
    }
}

// ============================================================================
// 256-wide NON-swizzled packs (r13-verified layout) for mlp3/head fused
// ============================================================================
__global__ __launch_bounds__(256) void pack256_3(
    const float* __restrict__ s0, u16* __restrict__ d0,
    const float* __restrict__ s1, u16* __restrict__ d1,
    const float* __restrict__ s2, u16* __restrict__ d2) {
    const float* s; u16* d;
    switch (blockIdx.y) {
        case 0: s = s0; d = d0; break;
        case 1: s = s1; d = d1; break;
        default: s = s2; d = d2; break;
    }
    int kt = blockIdx.x;
#pragma unroll
    for (int h = 0; h < 4; ++h) {
        int tid2 = threadIdx.x + h * 256;
        int n = tid2 >> 2;
        int k = kt * 32 + (tid2 & 3) * 8;
        u16x8 pk;
#pragma unroll
        for (int e = 0; e < 8; ++e) pk[e] = f2bf(s[(size_t)(k + e) * 256 + n]);
        *(u16x8*)(d + (size_t)kt * 8192 + (size_t)tid2 * 8) = pk;
    }
}

// ============================================================================
// SWIZZLED 256-wide packs for mlp2_fused (r14-verified): granule position
// p of row n holds k-chunk p^(n&3)
// ============================================================================
__global__ __launch_bounds__(256) void pack256s(const float* __restrict__ s,
                                                u16* __restrict__ d) {
    int kt = blockIdx.x;
#pragma unroll
    for (int h = 0; h < 4; ++h) {
        int tid2 = threadIdx.x + h * 256;
        int n = tid2 >> 2;
        int g = (tid2 & 3) ^ ((tid2 >> 2) & 3);
        int k = kt * 32 + g * 8;
        u16x8 pk;
#pragma unroll
        for (int e = 0; e < 8; ++e) pk[e] = f2bf(s[(size_t)(k + e) * 256 + n]);
        *(u16x8*)(d + (size_t)kt * 8192 + (size_t)tid2 * 8) = pk;
    }
}

// w2a swizzled pack, K=512, BN1 scale folded (scsh1 computed INLINE from sums)
__global__ __launch_bounds__(256) void pack256s_w2a(const float* __restrict__ w2a,
                                                    const float* __restrict__ sums,
                                                    const float* __restrict__ g1,
                                                    u16* __restrict__ d) {
    int kt = blockIdx.x;
#pragma unroll
    for (int h = 0; h < 4; ++h) {
        int tid2 = threadIdx.x + h * 256;
        int n = tid2 >> 2;
        int g = (tid2 & 3) ^ ((tid2 >> 2) & 3);
        int k = kt * 32 + g * 8;
        u16x8 pk;
#pragma unroll
        for (int e = 0; e < 8; ++e) {
            int c = (k + e) & 255;
            float mu = sums[c] * INV_R1;
            float var = sums[256 + c] * INV_R1 - mu * mu;
            float sc = g1[c] * rsqrtf(var + 1e-5f);
            pk[e] = f2bf(sc * w2a[(size_t)(k + e) * 256 + n]);
        }
        *(u16x8*)(d + (size_t)kt * 8192 + (size_t)tid2 * 8) = pk;
    }
}

__global__ void zero_stats(float* p, int n) {
    int i = blockIdx.x * 256 + threadIdx.x;
    if (i < n) p[i] = 0.f;
}

// BN1 shift term folded into fc1 bias (shift computed INLINE from sums)
__global__ __launch_bounds__(256) void fold_b2a(const float* __restrict__ w2a,
                                                const float* __restrict__ sums,
                                                const float* __restrict__ g1,
                                                const float* __restrict__ be1,
                                                const float* __restrict__ b2a,
                                                float* __restrict__ b2aF) {
    __shared__ float red[256];
    int n = blockIdx.x, tid = threadIdx.x;
    float mu = sums[tid] * INV_R1;
    float var = sums[256 + tid] * INV_R1 - mu * mu;
    float sc = g1[tid] * rsqrtf(var + 1e-5f);
    float sh = be1[tid] - mu * sc;
    float s = sh * w2a[tid * 256 + n] + sh * w2a[(tid + 256) * 256 + n];
    red[tid] = s;
    __syncthreads();
    for (int off2 = 128; off2 > 0; off2 >>= 1) {
        if (tid < off2) red[tid] += red[tid + off2];
        __syncthreads();
    }
    if (tid == 0) b2aF[n] = red[0] + b2a[n];
}

// -------------------- mlp1 fc1: K=4, VALU (verified) -------------------------
__global__ __launch_bounds__(256) void mlp1_fc1(const float* __restrict__ x,
                                                const float* __restrict__ w1a,
                                                const float* __restrict__ b1a,
                                                u16* __restrict__ ha) {
    int tid = threadIdx.x;
    int row = blockIdx.x * 8 + (tid >> 5);
    int ch8 = (tid & 31) * 8;
    int b = row / (NV * TT);
    int v = (row >> 6) % NV;
    int t = row & 63;
    const float* xp = x + ((size_t)(b * TT + t) * NV + v) * 4;
    float x0 = xp[0], x1 = xp[1], x2 = xp[2], x3 = xp[3];
    u16x8 pack;
#pragma unroll
    for (int e = 0; e < 8; ++e) {
        int c = ch8 + e;
        float acc = b1a[c] + x0 * w1a[c] + x1 * w1a[256 + c] + x2 * w1a[512 + c] + x3 * w1a[768 + c];
        pack[e] = f2bf(elu(acc));
    }
    *(u16x8*)(ha + (size_t)row * 256 + ch8) = pack;
}

// ============================================================================
// 128x128 engine (r8-verified, packed-B) — mlp1 fc2. UNCHANGED.
// ============================================================================
template <int ACT, bool STATS>
__global__ __launch_bounds__(256) void gemm_kernel(const u16* __restrict__ A,
                                                   const u16* __restrict__ Wt,
                                                   const float* __restrict__ bias,
                                                   u16* __restrict__ out,
                                                   int K,
                                                   float* __restrict__ stats) {
    __shared__ u16 As[3][128 * 32];
    __shared__ u16 Bs[3][128 * 32];
    const int tid = threadIdx.x;
    const int lane = tid & 63, wid = tid >> 6;

    int bm, bn;
    {
        int bid = blockIdx.x;
        int xcd = bid & 7, slot = bid >> 3;
        bn = slot & 1;
        bm = xcd + 8 * (slot >> 1);
    }
    const int m0 = bm * 128, n0 = bn * 128;
    const int wm = wid >> 1, wn = wid & 1;

    const int srow = tid >> 2;
    const int scol8 = (tid & 3) * 8;

    size_t abase0 = (size_t)(m0 + srow) * K;
    size_t abase1 = (size_t)(m0 + srow + 64) * K;
    const int NT = K >> 5;
    const size_t bnbase = (size_t)bn * NT * 4096;

    f32x4 acc[4][4];
#pragma unroll
    for (int i = 0; i < 4; ++i)
#pragma unroll
        for (int j = 0; j < 4; ++j) acc[i][j] = (f32x4)0.f;

    const int lrow = lane & 15;
    const int lk8 = (lane >> 4) * 8;

    auto stage = [&](int bf, int k0) {
        const size_t btile = bnbase + (size_t)(k0 >> 5) * 4096 + (size_t)tid * 8;
        GLL(A + abase0 + k0 + scol8, &As[bf][(wid * 64) * 8]);
        GLL(Wt + btile, &Bs[bf][(wid * 64) * 8]);
        GLL(A + abase1 + k0 + scol8, &As[bf][(256 + wid * 64) * 8]);
        GLL(Wt + btile + 2048, &Bs[bf][(256 + wid * 64) * 8]);
    };

    stage(0, 0);
    stage(1, 32);
    for (int kt = 0; kt < NT; ++kt) {
        if (kt + 1 < NT) {
            asm volatile("s_waitcnt vmcnt(4)" ::: "memory");
        } else {
            asm volatile("s_waitcnt vmcnt(0)" ::: "memory");
        }
        __builtin_amdgcn_s_barrier();
        if (kt + 2 < NT) stage((kt + 2) % 3, (kt + 2) * 32);
        __builtin_amdgcn_sched_barrier(0);
        const int buf = kt % 3;
        bf16x8 a[4], b[4];
#pragma unroll
        for (int i = 0; i < 4; ++i)
            a[i] = *(const bf16x8*)&As[buf][(wm * 64 + i * 16 + lrow) * 32 + lk8];
#pragma unroll
        for (int j = 0; j < 4; ++j)
            b[j] = *(const bf16x8*)&Bs[buf][(wn * 64 + j * 16 + lrow) * 32 + lk8];
#pragma unroll
        for (int i = 0; i < 4; ++i)
#pragma unroll
            for (int j = 0; j < 4; ++j)
                acc[i][j] = __builtin_amdgcn_mfma_f32_16x16x32_bf16(a[i], b[j], acc[i][j], 0, 0, 0);
    }

    float bv[4], sv[4], qv[4];
#pragma unroll
    for (int j = 0; j < 4; ++j) {
        bv[j] = bias[n0 + wn * 64 + j * 16 + lrow];
        if constexpr (STATS) { sv[j] = 0.f; qv[j] = 0.f; }
    }
#pragma unroll
    for (int i = 0; i < 4; ++i) {
#pragma unroll
        for (int j = 0; j < 4; ++j) {
            int col = n0 + wn * 64 + j * 16 + lrow;
#pragma unroll
            for (int r = 0; r < 4; ++r) {
                int row = m0 + wm * 64 + i * 16 + (lane >> 4) * 4 + r;
                float v = acc[i][j][r] + bv[j];
                v = (ACT == 1) ? elu(v) : (v > 0.f ? v : 0.f);
                if constexpr (STATS) { sv[j] += v; qv[j] += v * v; }
                out[(size_t)row * 256 + col] = f2bf(v);
            }
        }
    }
    if constexpr (STATS) {
#pragma unroll
        for (int j = 0; j < 4; ++j) {
            float s = sv[j], q_ = qv[j];
            s += __shfl_xor(s, 16); q_ += __shfl_xor(q_, 16);
            s += __shfl_xor(s, 32); q_ += __shfl_xor(q_, 32);
            if ((lane >> 4) == 0) {
                int col = n0 + wn * 64 + j * 16 + lrow;
                atomicAdd(&stats[col], s);
                atomicAdd(&stats[256 + col], q_);
            }
        }
    }
}

// ============================================================================
// mlp2_fused v5 — r15 dataflow with 1024 threads / 16 waves (4 waves/SIMD).
// Same block tile M=128 N=256, same LDS/pipeline/swizzles/epilogue math;
// wave grid 4M x 4N (wave tile 32x64, acc[2][4]). Staging: A by waves 0-7
// (512 thr x 16B = 4KB A-tile), B by all 16 waves (1024 thr x 16B = 8KB
// pack image). Counted vmcnt per wave group: fc1 {A-group 2, B-group 1},
// fc2 {1}. Doubles waves/SIMD 2 -> 4 for latency hiding (the remaining
// un-falsified bottleneck: all pipes idle at 23-32%).
// ============================================================================
__global__ __launch_bounds__(1024) void mlp2_fused(const u16* __restrict__ A,
                                                   const u16* __restrict__ PB1,
                                                   const float* __restrict__ bias1,
                                                   const u16* __restrict__ PB2,
                                                   const float* __restrict__ bias2,
                                                   u16* __restrict__ out,
                                                   float* __restrict__ stats) {
    __shared__ u16 As[3][128 * 32];    // 24 KB
    __shared__ u16 Bs[3][256 * 32];    // 48 KB
    __shared__ u16 H1[128 * 256];      // 64 KB

    const int tid = threadIdx.x;
    const int lane = tid & 63, wid = tid >> 6;     // 16 waves

    int bid = blockIdx.x;
    int xcd = bid & 7, slot = bid >> 3;            // 1440 = 8*180
    int batch = xcd + 8 * (slot / 45);
    int bm = batch * 45 + (slot % 45);
    const int m0 = bm * 128;
    const int wm = wid >> 2, wn = wid & 3;          // 4M x 4N wave grid

    // gather bases: only waves 0-7 stage A (row = tid>>2 in 0..127)
    size_t sb = 0, rb = 0;
    if (wid < 8) {
        int m = m0 + (tid >> 2);
        int t = m & 63, be = m >> 6, e = be % NE, b = be / NE;
        int s = e / 9, kk = e - s * 9, r = kk + (kk >= s ? 1 : 0);
        int achk = (tid & 3) ^ ((tid >> 2) & 3);   // source granule swizzle
        sb = ((size_t)((b * NV + s) * TT + t)) * 256 + achk * 8;
        rb = ((size_t)((b * NV + r) * TT + t)) * 256 + achk * 8;
    }

    const int lrow = lane & 15;
    const int lsw = (((lane >> 4) ^ (lrow & 3))) * 8;   // swizzled read granule

    f32x4 acc[2][4];
#pragma unroll
    for (int i = 0; i < 2; ++i)
#pragma unroll
        for (int j = 0; j < 4; ++j) acc[i][j] = (f32x4)0.f;

    auto stage1 = [&](int bf, int k0) {
        if (wid < 8)
            GLL(A + (k0 < 256 ? sb : rb) + (k0 & 255), &As[bf][tid * 8]);
        GLL(PB1 + (size_t)(k0 >> 5) * 8192 + (size_t)tid * 8, &Bs[bf][tid * 8]);
    };
    auto stage2 = [&](int bf, int k0) {
        GLL(PB2 + (size_t)(k0 >> 5) * 8192 + (size_t)tid * 8, &Bs[bf][tid * 8]);
    };

    // ---------------- fc1: K=512, NT=16 ----------------
    stage1(0, 0);
    stage1(1, 32);
    for (int kt = 0; kt < 16; ++kt) {
        if (kt + 1 < 16) {
            if (wid < 8) { asm volatile("s_waitcnt vmcnt(2)" ::: "memory"); }
            else         { asm volatile("s_waitcnt vmcnt(1)" ::: "memory"); }
        } else {
            asm volatile("s_waitcnt vmcnt(0)" ::: "memory");
        }
        __builtin_amdgcn_s_barrier();
        if (kt + 2 < 16) stage1((kt + 2) % 3, (kt + 2) * 32);
        __builtin_amdgcn_sched_barrier(0);
        const int buf = kt % 3;
        bf16x8 a[2], b[4];
#pragma unroll
        for (int i = 0; i < 2; ++i)
            a[i] = *(const bf16x8*)&As[buf][(wm * 32 + i * 16 + lrow) * 32 + lsw];
#pragma unroll
        for (int j = 0; j < 4; ++j)
            b[j] = *(const bf16x8*)&Bs[buf][(wn * 64 + j * 16 + lrow) * 32 + lsw];
#pragma unroll
        for (int i = 0; i < 2; ++i)
#pragma unroll
            for (int j = 0; j < 4; ++j)
                acc[i][j] = __builtin_amdgcn_mfma_f32_16x16x32_bf16(a[i], b[j], acc[i][j], 0, 0, 0);
    }

    // publish; issue fc2's first B-stages so GLL latency hides under epilogue
    __builtin_amdgcn_s_barrier();
    stage2(0, 0);
    stage2(1, 32);
    __builtin_amdgcn_sched_barrier(0);

    // ---- fc1 epilogue -> H1 (scalar swizzled writes, verified pattern) ----
#pragma unroll
    for (int j = 0; j < 4; ++j) {
        int c = wn * 64 + j * 16 + lrow;
        float bv = bias1[c];
        int gx = c >> 3;
        int cl = c & 7;
#pragma unroll
        for (int i = 0; i < 2; ++i) {
#pragma unroll
            for (int r = 0; r < 4; ++r) {
                int m = wm * 32 + i * 16 + (lane >> 4) * 4 + r;
                float v = elu(acc[i][j][r] + bv);
                H1[m * 256 + ((gx ^ (m & 7)) << 3) + cl] = f2bf(v);
            }
        }
    }
    __syncthreads();   // H1 published; stage2 GLLs flew under the epilogue

    // ---------------- fc2: K=256, NT=8, A from H1 ----------------
#pragma unroll
    for (int i = 0; i < 2; ++i)
#pragma unroll
        for (int j = 0; j < 4; ++j) acc[i][j] = (f32x4)0.f;

    for (int kt = 0; kt < 8; ++kt) {
        if (kt + 1 < 8) {
            asm volatile("s_waitcnt vmcnt(1)" ::: "memory");
        } else {
            asm volatile("s_waitcnt vmcnt(0)" ::: "memory");
        }
        __builtin_amdgcn_s_barrier();
        if (kt + 2 < 8) stage2((kt + 2) % 3, (kt + 2) * 32);
        __builtin_amdgcn_sched_barrier(0);
        const int buf = kt % 3;
        const int k0 = kt * 32;
        bf16x8 a[2], b[4];
#pragma unroll
        for (int i = 0; i < 2; ++i) {
            int mr = wm * 32 + i * 16 + lrow;
            int gx = (k0 >> 3) + (lane >> 4);
            a[i] = *(const bf16x8*)&H1[mr * 256 + ((gx ^ (mr & 7)) << 3)];
        }
#pragma unroll
        for (int j = 0; j < 4; ++j)
            b[j] = *(const bf16x8*)&Bs[buf][(wn * 64 + j * 16 + lrow) * 32 + lsw];
#pragma unroll
        for (int i = 0; i < 2; ++i)
#pragma unroll
            for (int j = 0; j < 4; ++j)
                acc[i][j] = __builtin_amdgcn_mfma_f32_16x16x32_bf16(a[i], b[j], acc[i][j], 0, 0, 0);
    }

    // ---- fc2 epilogue: scalar stores + shfl(16/32) stats (verified) ----
    float bv2[4], sv[4], qv[4];
#pragma unroll
    for (int j = 0; j < 4; ++j) {
        bv2[j] = bias2[wn * 64 + j * 16 + lrow];
        sv[j] = 0.f;
        qv[j] = 0.f;
    }
#pragma unroll
    for (int i = 0; i < 2; ++i) {
#pragma unroll
        for (int j = 0; j < 4; ++j) {
            int col = wn * 64 + j * 16 + lrow;
#pragma unroll
            for (int r = 0; r < 4; ++r) {
                int row = m0 + wm * 32 + i * 16 + (lane >> 4) * 4 + r;
                float v = elu(acc[i][j][r] + bv2[j]);
                sv[j] += v;
                qv[j] += v * v;
                out[(size_t)row * 256 + col] = f2bf(v);
            }
        }
    }
#pragma unroll
    for (int j = 0; j < 4; ++j) {
        float s = sv[j], q_ = qv[j];
        s += __shfl_xor(s, 16); q_ += __shfl_xor(q_, 16);
        s += __shfl_xor(s, 32); q_ += __shfl_xor(q_, 32);
        if ((lane >> 4) == 0) {
            int col = wn * 64 + j * 16 + lrow;
            atomicAdd(&stats[col], s);
            atomicAdd(&stats[256 + col], q_);
        }
    }
}

// ============================================================================
// mlp3_fused — r15 verbatim (verified).
// ============================================================================
__global__ __launch_bounds__(256) void mlp3_fused(const u16* __restrict__ A,
                                                  const u16* __restrict__ PB1,
                                                  const float* __restrict__ bias1,
                                                  const u16* __restrict__ PB2,
                                                  const float* __restrict__ bias2,
                                                  u16* __restrict__ out,
                                                  float* __restrict__ stats) {
    __shared__ u16 As[2][64 * 32];
    __shared__ u16 Bs[2][256 * 32];
    __shared__ u16 H1[64 * 256];

    const int tid = threadIdx.x;
    const int lane = tid & 63, wid = tid >> 6;
    int bid = blockIdx.x;
    int bm = (bid & 7) * 40 + (bid >> 3);
    const int m0 = bm * 64;
    const int wn = wid;

    const size_t ab = (size_t)(m0 + (tid >> 2)) * 256 + (tid & 3) * 8;

    const int lrow = lane & 15;
    const int lk8 = (lane >> 4) * 8;

    f32x4 acc[4][4];
#pragma unroll
    for (int i = 0; i < 4; ++i)
#pragma unroll
        for (int j = 0; j < 4; ++j) acc[i][j] = (f32x4)0.f;

    auto stage1 = [&](int bf, int k0) {
        GLL(A + ab + k0, &As[bf][tid * 8]);
        const u16* b_ = PB1 + (size_t)(k0 >> 5) * 8192;
#pragma unroll
        for (int q = 0; q < 4; ++q)
            GLL(b_ + (q * 256 + tid) * 8, &Bs[bf][(q * 256 + tid) * 8]);
    };
    auto stage2 = [&](int bf, int k0) {
        const u16* b_ = PB2 + (size_t)(k0 >> 5) * 8192;
#pragma unroll
        for (int q = 0; q < 4; ++q)
            GLL(b_ + (q * 256 + tid) * 8, &Bs[bf][(q * 256 + tid) * 8]);
    };

    stage1(0, 0);
    __syncthreads();
    for (int kt = 0; kt < 8; ++kt) {
        if (kt + 1 < 8) stage1((kt + 1) & 1, (kt + 1) * 32);
        const int buf = kt & 1;
        bf16x8 a[4], b[4];
#pragma unroll
        for (int i = 0; i < 4; ++i)
            a[i] = *(const bf16x8*)&As[buf][(i * 16 + lrow) * 32 + lk8];
#pragma unroll
        for (int j = 0; j < 4; ++j)
            b[j] = *(const bf16x8*)&Bs[buf][(wn * 64 + j * 16 + lrow) * 32 + lk8];
#pragma unroll
        for (int i = 0; i < 4; ++i)
#pragma unroll
            for (int j = 0; j < 4; ++j)
                acc[i][j] = __builtin_amdgcn_mfma_f32_16x16x32_bf16(a[i], b[j], acc[i][j], 0, 0, 0);
        __syncthreads();
    }

    stage2(0, 0);
    __builtin_amdgcn_sched_barrier(0);

#pragma unroll
    for (int j = 0; j < 4; ++j) {
        int c = wn * 64 + j * 16 + lrow;
        float bv = bias1[c];
        int gx = c >> 3;
        int cl = c & 7;
#pragma unroll
        for (int i = 0; i < 4; ++i) {
#pragma unroll
            for (int r = 0; r < 4; ++r) {
                int m = i * 16 + (lane >> 4) * 4 + r;
                float v = elu(acc[i][j][r] + bv);
                H1[m * 256 + ((gx ^ (m & 7)) << 3) + cl] = f2bf(v);
            }
        }
    }
    __syncthreads();

#pragma unroll
    for (int i = 0; i < 4; ++i)
#pragma unroll
        for (int j = 0; j < 4; ++j) acc[i][j] = (f32x4)0.f;

    for (int kt = 0; kt < 8; ++kt) {
        if (kt + 1 < 8) stage2((kt + 1) & 1, (kt + 1) * 32);
        const int buf = kt & 1;
        const int k0 = kt * 32;
        bf16x8 a[4], b[4];
#pragma unroll
        for (int i = 0; i < 4; ++i) {
            int mr = i * 16 + lrow;
            int gx = (k0 >> 3) + (lane >> 4);
            a[i] = *(const bf16x8*)&H1[mr * 256 + ((gx ^ (mr & 7)) << 3)];
        }
#pragma unroll
        for (int j = 0; j < 4; ++j)
            b[j] = *(const bf16x8*)&Bs[buf][(wn * 64 + j * 16 + lrow) * 32 + lk8];
#pragma unroll
        for (int i = 0; i < 4; ++i)
#pragma unroll
            for (int j = 0; j < 4; ++j)
                acc[i][j] = __builtin_amdgcn_mfma_f32_16x16x32_bf16(a[i], b[j], acc[i][j], 0, 0, 0);
        __syncthreads();
    }

    float bv2[4], sv[4], qv[4];
#pragma unroll
    for (int j = 0; j < 4; ++j) {
        bv2[j] = bias2[wn * 64 + j * 16 + lrow];
        sv[j] = 0.f;
        qv[j] = 0.f;
    }
#pragma unroll
    for (int i = 0; i < 4; ++i) {
#pragma unroll
        for (int j = 0; j < 4; ++j) {
            int col = wn * 64 + j * 16 + lrow;
#pragma unroll
            for (int r = 0; r < 4; ++r) {
                int row = m0 + i * 16 + (lane >> 4) * 4 + r;
                float v = elu(acc[i][j][r] + bv2[j]);
                sv[j] += v;
                qv[j] += v * v;
                out[(size_t)row * 256 + col] = f2bf(v);
            }
        }
    }
#pragma unroll
    for (int j = 0; j < 4; ++j) {
        float s = sv[j], q_ = qv[j];
        s += __shfl_xor(s, 16); q_ += __shfl_xor(q_, 16);
        s += __shfl_xor(s, 32); q_ += __shfl_xor(q_, 32);
        if ((lane >> 4) == 0) {
            int col = wn * 64 + j * 16 + lrow;
            atomicAdd(&stats[col], s);
            atomicAdd(&stats[256 + col], q_);
        }
    }
}

// ============================================================================
// head_fused — r15 verbatim (verified).
// ============================================================================
__global__ __launch_bounds__(256) void head_fused(const u16* __restrict__ A,
                                                  const u16* __restrict__ PB1,
                                                  const float* __restrict__ bo1,
                                                  const float* __restrict__ wo2,
                                                  const float* __restrict__ bo2,
                                                  float* __restrict__ out) {
    __shared__ u16 As[2][64 * 32];
    __shared__ u16 Bs[2][256 * 32];
    __shared__ float rs[64 * 4];

    const int tid = threadIdx.x;
    const int lane = tid & 63, wid = tid >> 6;
    int bid = blockIdx.x;
    int bm = (bid & 7) * 40 + (bid >> 3);
    const int m0 = bm * 64;
    const int wn = wid;

    const size_t ab = (size_t)(m0 + (tid >> 2)) * 256 + (tid & 3) * 8;

    const int lrow = lane & 15;
    const int lk8 = (lane >> 4) * 8;

    f32x4 acc[4][4];
#pragma unroll
    for (int i = 0; i < 4; ++i)
#pragma unroll
        for (int j = 0; j < 4; ++j) acc[i][j] = (f32x4)0.f;

    auto stage1 = [&](int bf, int k0) {
        GLL(A + ab + k0, &As[bf][tid * 8]);
        const u16* b_ = PB1 + (size_t)(k0 >> 5) * 8192;
#pragma unroll
        for (int q = 0; q < 4; ++q)
            GLL(b_ + (q * 256 + tid) * 8, &Bs[bf][(q * 256 + tid) * 8]);
    };

    stage1(0, 0);
    __syncthreads();
    for (int kt = 0; kt < 8; ++kt) {
        if (kt + 1 < 8) stage1((kt + 1) & 1, (kt + 1) * 32);
        const int buf = kt & 1;
        bf16x8 a[4], b[4];
#pragma unroll
        for (int i = 0; i < 4; ++i)
            a[i] = *(const bf16x8*)&As[buf][(i * 16 + lrow) * 32 + lk8];
#pragma unroll
        for (int j = 0; j < 4; ++j)
            b[j] = *(const bf16x8*)&Bs[buf][(wn * 64 + j * 16 + lrow) * 32 + lk8];
#pragma unroll
        for (int i = 0; i < 4; ++i)
#pragma unroll
            for (int j = 0; j < 4; ++j)
                acc[i][j] = __builtin_amdgcn_mfma_f32_16x16x32_bf16(a[i], b[j], acc[i][j], 0, 0, 0);
        __syncthreads();
    }

    float p[4][4];
#pragma unroll
    for (int i = 0; i < 4; ++i)
#pragma unroll
        for (int r = 0; r < 4; ++r) p[i][r] = 0.f;
#pragma unroll
    for (int j = 0; j < 4; ++j) {
        int col = wn * 64 + j * 16 + lrow;
        float bv = bo1[col];
        float w = wo2[col];
#pragma unroll
        for (int i = 0; i < 4; ++i) {
#pragma unroll
            for (int r = 0; r < 4; ++r) {
                float v = acc[i][j][r] + bv;
                v = v > 0.f ? v : 0.f;
                p[i][r] += v * w;
            }
        }
    }
#pragma unroll
    for (int i = 0; i < 4; ++i) {
#pragma unroll
        for (int r = 0; r < 4; ++r) {
            float s = p[i][r];
            s += __shfl_xor(s, 1);
            s += __shfl_xor(s, 2);
            s += __shfl_xor(s, 4);
            s += __shfl_xor(s, 8);
            p[i][r] = s;
        }
    }
    if (lrow == 0) {
#pragma unroll
        for (int i = 0; i < 4; ++i)
#pragma unroll
            for (int r = 0; r < 4; ++r) {
                int rowlocal = i * 16 + (lane >> 4) * 4 + r;
                rs[rowlocal * 4 + wn] = p[i][r];
            }
    }
    __syncthreads();
    if (tid < 64) {
        float s = rs[tid * 4] + rs[tid * 4 + 1] + rs[tid * 4 + 2] + rs[tid * 4 + 3] + bo2[0];
        int m = m0 + tid;
        int b = m / (NV * TT);
        int v = (m >> 6) % NV;
        int t = m & 63;
        out[(size_t)(b * TT + t) * NV + v] = s;
    }
}

// -------------------- BN3 affine + relu (scsh computed inline) ---------------
__global__ __launch_bounds__(256) void norm_affine_relu(const u16* __restrict__ in,
                                                        const float* __restrict__ sums,
                                                        const float* __restrict__ g3,
                                                        const float* __restrict__ be3,
                                                        u16* __restrict__ out, int n8) {
    int i = blockIdx.x * 256 + threadIdx.x;
    if (i >= n8) return;
    size_t base = (size_t)i * 8;
    int ch8 = (int)(base & 255);
    u16x8 v = *(const u16x8*)(in + base);
    u16x8 o;
#pragma unroll
    for (int e = 0; e < 8; ++e) {
        int c = ch8 + e;
        float mu = sums[c] * INV_R1;
        float var = sums[256 + c] * INV_R1 - mu * mu;
        float sc = g3[c] * rsqrtf(var + 1e-5f);
        float sh = be3[c] - mu * sc;
        float f = bf2f(v[e]) * sc + sh;
        o[e] = f2bf(f > 0.f ? f : 0.f);
    }
    *(u16x8*)(out + base) = o;
}

// -------------------- edge2node: incidence sum + BN2 affine (inline scsh) ----
__global__ __launch_bounds__(256) void edge2node(const u16* __restrict__ h2,
                                                 const float* __restrict__ sums,
                                                 const float* __restrict__ g2,
                                                 const float* __restrict__ be2,
                                                 u16* __restrict__ n1) {
    int tid = threadIdx.x;
    int row = blockIdx.x * 8 + (tid >> 5);
    int ch8 = (tid & 31) * 8;
    int t = row & 63;
    int bv = row >> 6;
    int v = bv % NV;
    int b = bv / NV;
    float acc[8] = {0, 0, 0, 0, 0, 0, 0, 0};
#pragma unroll
    for (int i = 0; i < 9; ++i) {
        int s = i + (i >= v ? 1 : 0);
        int e = s * 9 + (v < s ? v : v - 1);
        u16x8 vv = *(const u16x8*)(h2 + ((size_t)((b * NE + e) * TT + t)) * 256 + ch8);
#pragma unroll
        for (int k = 0; k < 8; ++k) acc[k] += bf2f(vv[k]);
    }
    const float inv9 = 1.f / 9.f;
    u16x8 o;
#pragma unroll
    for (int k = 0; k < 8; ++k) {
        int c = ch8 + k;
        float mu = sums[c] * INV_R2;
        float var = sums[256 + c] * INV_R2 - mu * mu;
        float sc = g2[c] * rsqrtf(var + 1e-5f);
        float sh = be2[c] - mu * sc;
        o[k] = f2bf(sc * (acc[k] * inv9) + sh);
    }
    *(u16x8*)(n1 + (size_t)row * 256 + ch8) = o;
}

extern "C" void kernel_launch(void* const* d_in, const int* in_sizes, int n_in,
                              void* d_out, int out_size, void* d_ws, size_t ws_size,
                              hipStream_t stream) {
    const float* x   = (const float*)d_in[0];
    const float* w1a = (const float*)d_in[1];
    const float* b1a = (const float*)d_in[2];
    const float* w1b = (const float*)d_in[3];
    const float* b1b = (const float*)d_in[4];
    const float* g1  = (const float*)d_in[5];
    const float* be1 = (const float*)d_in[6];
    const float* w2a = (const float*)d_in[7];
    const float* b2a = (const float*)d_in[8];
    const float* w2b = (const float*)d_in[9];
    const float* b2b = (const float*)d_in[10];
    const float* g2  = (const float*)d_in[11];
    const float* be2 = (const float*)d_in[12];
    const float* w3a = (const float*)d_in[13];
    const float* b3a = (const float*)d_in[14];
    const float* w3b = (const float*)d_in[15];
    const float* b3b = (const float*)d_in[16];
    const float* g3  = (const float*)d_in[17];
    const float* be3 = (const float*)d_in[18];
    const float* wo1 = (const float*)d_in[19];
    const float* bo1 = (const float*)d_in[20];
    const float* wo2 = (const float*)d_in[21];
    const float* bo2 = (const float*)d_in[22];
    float* out = (float*)d_out;

    char* ws = (char*)d_ws;
    size_t off = 0;
    auto alloc = [&](size_t bytes) {
        void* p = ws + off;
        off = (off + bytes + 255) & ~(size_t)255;
        return p;
    };
    u16* w1bP = (u16*)alloc(2 * 8 * 4096 * 2);
    u16* w3aP = (u16*)alloc(8 * 8192 * 2);
    u16* w3bP = (u16*)alloc(8 * 8192 * 2);
    u16* wo1P = (u16*)alloc(8 * 8192 * 2);
    u16* w2aP = (u16*)alloc(16 * 8192 * 2);
    u16* w2bP = (u16*)alloc(8 * 8192 * 2);
    float* sums  = (float*)alloc(3 * 512 * 4);
    float* b2aF  = (float*)alloc(256 * 4);
    u16* S0 = (u16*)alloc((size_t)R1 * 256 * 2);
    u16* S1 = (u16*)alloc((size_t)R1 * 256 * 2);
    u16* S2 = (u16*)alloc((size_t)R1 * 256 * 2);
    u16* BIG2 = (u16*)alloc((size_t)R2 * 256 * 2);

    pack128<<<16, 256, 0, stream>>>(w1b, w1bP);
    dim3 p3grid(8, 3);
    pack256_3<<<p3grid, 256, 0, stream>>>(w3a, w3aP, w3b, w3bP, wo1, wo1P);
    pack256s<<<8, 256, 0, stream>>>(w2b, w2bP);
    zero_stats<<<6, 256, 0, stream>>>(sums, 3 * 512);

    // mlp1: fc1 (VALU) + fc2 GEMM with fused stats
    mlp1_fc1<<<R1 / 8, 256, 0, stream>>>(x, w1a, b1a, S0);
    gemm_kernel<1, true><<<(R1 / 128) * 2, 256, 0, stream>>>(S0, w1bP, b1b, S1, 256, sums);
    pack256s_w2a<<<16, 256, 0, stream>>>(w2a, sums, g1, w2aP);
    fold_b2a<<<256, 256, 0, stream>>>(w2a, sums, g1, be1, b2a, b2aF);

    // mlp2: fused gather-fc1 + fc2, 16 waves (4/SIMD)
    mlp2_fused<<<R2 / 128, 1024, 0, stream>>>(S1, w2aP, b2aF, w2bP, b2b, BIG2, sums + 512);

    // edge2node (BN2 affine computed inline from sums)
    edge2node<<<R1 / 8, 256, 0, stream>>>(BIG2, sums + 512, g2, be2, S0);

    // mlp3: fused fc1+fc2, stats fused
    mlp3_fused<<<R1 / 64, 256, 0, stream>>>(S0, w3aP, b3a, w3bP, b3b, S2, sums + 1024);

    // head: BN3 affine+relu (inline scsh), then fused wo1 GEMM + dot wo2
    norm_affine_relu<<<(R1 * 32 + 255) / 256, 256, 0, stream>>>(S2, sums + 1024, g3, be3, S0, R1 * 32);
    head_fused<<<R1 / 64, 256, 0, stream>>>(S0, wo1P, bo1, wo2, bo2, out);
}

// Round 17
// 238.696 us; speedup vs baseline: 1.2251x; 1.2251x over previous
//
#include <hip/hip_runtime.h>
#include <hip/hip_bf16.h>
#include <cstdint>

#define DI __device__ __forceinline__

typedef short bf16x8 __attribute__((ext_vector_type(8)));
typedef float f32x4 __attribute__((ext_vector_type(4)));
typedef unsigned short u16;
typedef unsigned short u16x8 __attribute__((ext_vector_type(8)));

static constexpr int NV = 10, NE = 90, TT = 64;
static constexpr int R1 = 20480;   // 32*10*64 node rows
static constexpr int R2 = 184320;  // 32*90*64 edge rows
static constexpr float INV_R1 = 1.f / 20480.f;
static constexpr float INV_R2 = 1.f / 184320.f;

DI float bf2f(u16 u) { union { unsigned int i; float f; } x; x.i = ((unsigned int)u) << 16; return x.f; }
DI u16 f2bf(float f) { unsigned int u = __float_as_uint(f); return (u16)((u + 0x7FFF + ((u >> 16) & 1)) >> 16); }
DI float elu(float v) { return v > 0.f ? v : __expf(v) - 1.f; }

#define GLL(srcp, dstp) __builtin_amdgcn_global_load_lds( \
    (const __attribute__((address_space(1))) unsigned int*)(srcp), \
    (__attribute__((address_space(3))) unsigned int*)(dstp), 16, 0, 0)

// ============================================================================
// 128-tile weight packing (mlp1-fc2 gemm, r8-verified)
// ============================================================================
__global__ __launch_bounds__(256) void pack128(const float* __restrict__ s,
                                               u16* __restrict__ d) {
    int tid = threadIdx.x;
    int bn = blockIdx.x >> 3, kt = blockIdx.x & 7;
#pragma unroll
    for (int p = 0; p < 2; ++p) {
        int n = bn * 128 + p * 64 + (tid >> 2);
        int k = kt * 32 + (tid & 3) * 8;
        u16x8 pk;
#pragma unroll
        for (int e = 0; e < 8; ++e) pk[e] = f2bf(s[(size_t)(k + e) * 256 + n]);
        *(u16x8*)(d + ((size_t)((bn * 8 + kt) * 2 + p)) * 2048 + (size_t)tid * 8) = pk;
    }
}

// ============================================================================
// 256-wide NON-swizzled packs (r13-verified layout) for mlp3/head fused
// ============================================================================
__global__ __launch_bounds__(256) void pack256_3(
    const float* __restrict__ s0, u16* __restrict__ d0,
    const float* __restrict__ s1, u16* __restrict__ d1,
    const float* __restrict__ s2, u16* __restrict__ d2) {
    const float* s; u16* d;
    switch (blockIdx.y) {
        case 0: s = s0; d = d0; break;
        case 1: s = s1; d = d1; break;
        default: s = s2; d = d2; break;
    }
    int kt = blockIdx.x;
#pragma unroll
    for (int h = 0; h < 4; ++h) {
        int tid2 = threadIdx.x + h * 256;
        int n = tid2 >> 2;
        int k = kt * 32 + (tid2 & 3) * 8;
        u16x8 pk;
#pragma unroll
        for (int e = 0; e < 8; ++e) pk[e] = f2bf(s[(size_t)(k + e) * 256 + n]);
        *(u16x8*)(d + (size_t)kt * 8192 + (size_t)tid2 * 8) = pk;
    }
}

// ============================================================================
// SWIZZLED 256-wide packs for mlp2_fused (r14/r15-verified): granule position
// p of row n holds k-chunk p^(n&3)
// ============================================================================
__global__ __launch_bounds__(256) void pack256s(const float* __restrict__ s,
                                                u16* __restrict__ d) {
    int kt = blockIdx.x;
#pragma unroll
    for (int h = 0; h < 4; ++h) {
        int tid2 = threadIdx.x + h * 256;
        int n = tid2 >> 2;
        int g = (tid2 & 3) ^ ((tid2 >> 2) & 3);
        int k = kt * 32 + g * 8;
        u16x8 pk;
#pragma unroll
        for (int e = 0; e < 8; ++e) pk[e] = f2bf(s[(size_t)(k + e) * 256 + n]);
        *(u16x8*)(d + (size_t)kt * 8192 + (size_t)tid2 * 8) = pk;
    }
}

// w2a swizzled pack, K=512, BN1 scale folded (scsh1 computed INLINE from sums)
__global__ __launch_bounds__(256) void pack256s_w2a(const float* __restrict__ w2a,
                                                    const float* __restrict__ sums,
                                                    const float* __restrict__ g1,
                                                    u16* __restrict__ d) {
    int kt = blockIdx.x;
#pragma unroll
    for (int h = 0; h < 4; ++h) {
        int tid2 = threadIdx.x + h * 256;
        int n = tid2 >> 2;
        int g = (tid2 & 3) ^ ((tid2 >> 2) & 3);
        int k = kt * 32 + g * 8;
        u16x8 pk;
#pragma unroll
        for (int e = 0; e < 8; ++e) {
            int c = (k + e) & 255;
            float mu = sums[c] * INV_R1;
            float var = sums[256 + c] * INV_R1 - mu * mu;
            float sc = g1[c] * rsqrtf(var + 1e-5f);
            pk[e] = f2bf(sc * w2a[(size_t)(k + e) * 256 + n]);
        }
        *(u16x8*)(d + (size_t)kt * 8192 + (size_t)tid2 * 8) = pk;
    }
}

__global__ void zero_stats(float* p, int n) {
    int i = blockIdx.x * 256 + threadIdx.x;
    if (i < n) p[i] = 0.f;
}

// BN1 shift term folded into fc1 bias (shift computed INLINE from sums)
__global__ __launch_bounds__(256) void fold_b2a(const float* __restrict__ w2a,
                                                const float* __restrict__ sums,
                                                const float* __restrict__ g1,
                                                const float* __restrict__ be1,
                                                const float* __restrict__ b2a,
                                                float* __restrict__ b2aF) {
    __shared__ float red[256];
    int n = blockIdx.x, tid = threadIdx.x;
    float mu = sums[tid] * INV_R1;
    float var = sums[256 + tid] * INV_R1 - mu * mu;
    float sc = g1[tid] * rsqrtf(var + 1e-5f);
    float sh = be1[tid] - mu * sc;
    float s = sh * w2a[tid * 256 + n] + sh * w2a[(tid + 256) * 256 + n];
    red[tid] = s;
    __syncthreads();
    for (int off2 = 128; off2 > 0; off2 >>= 1) {
        if (tid < off2) red[tid] += red[tid + off2];
        __syncthreads();
    }
    if (tid == 0) b2aF[n] = red[0] + b2a[n];
}

// -------------------- mlp1 fc1: K=4, VALU (verified) -------------------------
__global__ __launch_bounds__(256) void mlp1_fc1(const float* __restrict__ x,
                                                const float* __restrict__ w1a,
                                                const float* __restrict__ b1a,
                                                u16* __restrict__ ha) {
    int tid = threadIdx.x;
    int row = blockIdx.x * 8 + (tid >> 5);
    int ch8 = (tid & 31) * 8;
    int b = row / (NV * TT);
    int v = (row >> 6) % NV;
    int t = row & 63;
    const float* xp = x + ((size_t)(b * TT + t) * NV + v) * 4;
    float x0 = xp[0], x1 = xp[1], x2 = xp[2], x3 = xp[3];
    u16x8 pack;
#pragma unroll
    for (int e = 0; e < 8; ++e) {
        int c = ch8 + e;
        float acc = b1a[c] + x0 * w1a[c] + x1 * w1a[256 + c] + x2 * w1a[512 + c] + x3 * w1a[768 + c];
        pack[e] = f2bf(elu(acc));
    }
    *(u16x8*)(ha + (size_t)row * 256 + ch8) = pack;
}

// ============================================================================
// 128x128 engine (r8-verified, packed-B) — mlp1 fc2. UNCHANGED.
// ============================================================================
template <int ACT, bool STATS>
__global__ __launch_bounds__(256) void gemm_kernel(const u16* __restrict__ A,
                                                   const u16* __restrict__ Wt,
                                                   const float* __restrict__ bias,
                                                   u16* __restrict__ out,
                                                   int K,
                                                   float* __restrict__ stats) {
    __shared__ u16 As[3][128 * 32];
    __shared__ u16 Bs[3][128 * 32];
    const int tid = threadIdx.x;
    const int lane = tid & 63, wid = tid >> 6;

    int bm, bn;
    {
        int bid = blockIdx.x;
        int xcd = bid & 7, slot = bid >> 3;
        bn = slot & 1;
        bm = xcd + 8 * (slot >> 1);
    }
    const int m0 = bm * 128, n0 = bn * 128;
    const int wm = wid >> 1, wn = wid & 1;

    const int srow = tid >> 2;
    const int scol8 = (tid & 3) * 8;

    size_t abase0 = (size_t)(m0 + srow) * K;
    size_t abase1 = (size_t)(m0 + srow + 64) * K;
    const int NT = K >> 5;
    const size_t bnbase = (size_t)bn * NT * 4096;

    f32x4 acc[4][4];
#pragma unroll
    for (int i = 0; i < 4; ++i)
#pragma unroll
        for (int j = 0; j < 4; ++j) acc[i][j] = (f32x4)0.f;

    const int lrow = lane & 15;
    const int lk8 = (lane >> 4) * 8;

    auto stage = [&](int bf, int k0) {
        const size_t btile = bnbase + (size_t)(k0 >> 5) * 4096 + (size_t)tid * 8;
        GLL(A + abase0 + k0 + scol8, &As[bf][(wid * 64) * 8]);
        GLL(Wt + btile, &Bs[bf][(wid * 64) * 8]);
        GLL(A + abase1 + k0 + scol8, &As[bf][(256 + wid * 64) * 8]);
        GLL(Wt + btile + 2048, &Bs[bf][(256 + wid * 64) * 8]);
    };

    stage(0, 0);
    stage(1, 32);
    for (int kt = 0; kt < NT; ++kt) {
        if (kt + 1 < NT) {
            asm volatile("s_waitcnt vmcnt(4)" ::: "memory");
        } else {
            asm volatile("s_waitcnt vmcnt(0)" ::: "memory");
        }
        __builtin_amdgcn_s_barrier();
        if (kt + 2 < NT) stage((kt + 2) % 3, (kt + 2) * 32);
        __builtin_amdgcn_sched_barrier(0);
        const int buf = kt % 3;
        bf16x8 a[4], b[4];
#pragma unroll
        for (int i = 0; i < 4; ++i)
            a[i] = *(const bf16x8*)&As[buf][(wm * 64 + i * 16 + lrow) * 32 + lk8];
#pragma unroll
        for (int j = 0; j < 4; ++j)
            b[j] = *(const bf16x8*)&Bs[buf][(wn * 64 + j * 16 + lrow) * 32 + lk8];
#pragma unroll
        for (int i = 0; i < 4; ++i)
#pragma unroll
            for (int j = 0; j < 4; ++j)
                acc[i][j] = __builtin_amdgcn_mfma_f32_16x16x32_bf16(a[i], b[j], acc[i][j], 0, 0, 0);
    }

    float bv[4], sv[4], qv[4];
#pragma unroll
    for (int j = 0; j < 4; ++j) {
        bv[j] = bias[n0 + wn * 64 + j * 16 + lrow];
        if constexpr (STATS) { sv[j] = 0.f; qv[j] = 0.f; }
    }
#pragma unroll
    for (int i = 0; i < 4; ++i) {
#pragma unroll
        for (int j = 0; j < 4; ++j) {
            int col = n0 + wn * 64 + j * 16 + lrow;
#pragma unroll
            for (int r = 0; r < 4; ++r) {
                int row = m0 + wm * 64 + i * 16 + (lane >> 4) * 4 + r;
                float v = acc[i][j][r] + bv[j];
                v = (ACT == 1) ? elu(v) : (v > 0.f ? v : 0.f);
                if constexpr (STATS) { sv[j] += v; qv[j] += v * v; }
                out[(size_t)row * 256 + col] = f2bf(v);
            }
        }
    }
    if constexpr (STATS) {
#pragma unroll
        for (int j = 0; j < 4; ++j) {
            float s = sv[j], q_ = qv[j];
            s += __shfl_xor(s, 16); q_ += __shfl_xor(q_, 16);
            s += __shfl_xor(s, 32); q_ += __shfl_xor(q_, 32);
            if ((lane >> 4) == 0) {
                int col = n0 + wn * 64 + j * 16 + lrow;
                atomicAdd(&stats[col], s);
                atomicAdd(&stats[256 + col], q_);
            }
        }
    }
}

// ============================================================================
// mlp2_fused — r15 VERBATIM (verified 133 us best): 512 thr / 8 waves,
// M=128 N=256, 3-buf counted vmcnt, swizzled As/Bs, scalar swizzled H1
// epilogue, scalar stores + shfl(16/32) stats. The 16-wave (r16) and
// M=64 (r13) variants both regressed — this is the measured local optimum
// of the wave-tile-reuse vs occupancy trade-off (LDS-read-port bound).
// ============================================================================
__global__ __launch_bounds__(512) void mlp2_fused(const u16* __restrict__ A,
                                                  const u16* __restrict__ PB1,
                                                  const float* __restrict__ bias1,
                                                  const u16* __restrict__ PB2,
                                                  const float* __restrict__ bias2,
                                                  u16* __restrict__ out,
                                                  float* __restrict__ stats) {
    __shared__ u16 As[3][128 * 32];    // 24 KB
    __shared__ u16 Bs[3][256 * 32];    // 48 KB
    __shared__ u16 H1[128 * 256];      // 64 KB

    const int tid = threadIdx.x;
    const int lane = tid & 63, wid = tid >> 6;     // 8 waves

    int bid = blockIdx.x;
    int xcd = bid & 7, slot = bid >> 3;            // 1440 = 8*180
    int batch = xcd + 8 * (slot / 45);
    int bm = batch * 45 + (slot % 45);
    const int m0 = bm * 128;
    const int wm = wid >> 2, wn = wid & 3;          // 2M x 4N wave grid

    size_t sb, rb;
    {
        int m = m0 + (tid >> 2);
        int t = m & 63, be = m >> 6, e = be % NE, b = be / NE;
        int s = e / 9, kk = e - s * 9, r = kk + (kk >= s ? 1 : 0);
        int achk = (tid & 3) ^ ((tid >> 2) & 3);
        sb = ((size_t)((b * NV + s) * TT + t)) * 256 + achk * 8;
        rb = ((size_t)((b * NV + r) * TT + t)) * 256 + achk * 8;
    }

    const int lrow = lane & 15;
    const int lsw = (((lane >> 4) ^ (lrow & 3))) * 8;

    f32x4 acc[4][4];
#pragma unroll
    for (int i = 0; i < 4; ++i)
#pragma unroll
        for (int j = 0; j < 4; ++j) acc[i][j] = (f32x4)0.f;

    auto stage1 = [&](int bf, int k0) {
        GLL(A + (k0 < 256 ? sb : rb) + (k0 & 255), &As[bf][tid * 8]);
        const u16* b_ = PB1 + (size_t)(k0 >> 5) * 8192 + (size_t)tid * 8;
        GLL(b_, &Bs[bf][tid * 8]);
        GLL(b_ + 4096, &Bs[bf][4096 + tid * 8]);
    };
    auto stage2 = [&](int bf, int k0) {
        const u16* b_ = PB2 + (size_t)(k0 >> 5) * 8192 + (size_t)tid * 8;
        GLL(b_, &Bs[bf][tid * 8]);
        GLL(b_ + 4096, &Bs[bf][4096 + tid * 8]);
    };

    // ---------------- fc1: K=512, NT=16 ----------------
    stage1(0, 0);
    stage1(1, 32);
    for (int kt = 0; kt < 16; ++kt) {
        if (kt + 1 < 16) {
            asm volatile("s_waitcnt vmcnt(3)" ::: "memory");
        } else {
            asm volatile("s_waitcnt vmcnt(0)" ::: "memory");
        }
        __builtin_amdgcn_s_barrier();
        if (kt + 2 < 16) stage1((kt + 2) % 3, (kt + 2) * 32);
        __builtin_amdgcn_sched_barrier(0);
        const int buf = kt % 3;
        bf16x8 a[4], b[4];
#pragma unroll
        for (int i = 0; i < 4; ++i)
            a[i] = *(const bf16x8*)&As[buf][(wm * 64 + i * 16 + lrow) * 32 + lsw];
#pragma unroll
        for (int j = 0; j < 4; ++j)
            b[j] = *(const bf16x8*)&Bs[buf][(wn * 64 + j * 16 + lrow) * 32 + lsw];
#pragma unroll
        for (int i = 0; i < 4; ++i)
#pragma unroll
            for (int j = 0; j < 4; ++j)
                acc[i][j] = __builtin_amdgcn_mfma_f32_16x16x32_bf16(a[i], b[j], acc[i][j], 0, 0, 0);
    }

    // publish; issue fc2's first B-stages so GLL latency hides under epilogue
    __builtin_amdgcn_s_barrier();
    stage2(0, 0);
    stage2(1, 32);
    __builtin_amdgcn_sched_barrier(0);

    // ---- fc1 epilogue -> H1 (scalar swizzled writes) ----
#pragma unroll
    for (int j = 0; j < 4; ++j) {
        int c = wn * 64 + j * 16 + lrow;
        float bv = bias1[c];
        int gx = c >> 3;
        int cl = c & 7;
#pragma unroll
        for (int i = 0; i < 4; ++i) {
#pragma unroll
            for (int r = 0; r < 4; ++r) {
                int m = wm * 64 + i * 16 + (lane >> 4) * 4 + r;
                float v = elu(acc[i][j][r] + bv);
                H1[m * 256 + ((gx ^ (m & 7)) << 3) + cl] = f2bf(v);
            }
        }
    }
    __syncthreads();

    // ---------------- fc2: K=256, NT=8, A from H1 ----------------
#pragma unroll
    for (int i = 0; i < 4; ++i)
#pragma unroll
        for (int j = 0; j < 4; ++j) acc[i][j] = (f32x4)0.f;

    for (int kt = 0; kt < 8; ++kt) {
        if (kt + 1 < 8) {
            asm volatile("s_waitcnt vmcnt(2)" ::: "memory");
        } else {
            asm volatile("s_waitcnt vmcnt(0)" ::: "memory");
        }
        __builtin_amdgcn_s_barrier();
        if (kt + 2 < 8) stage2((kt + 2) % 3, (kt + 2) * 32);
        __builtin_amdgcn_sched_barrier(0);
        const int buf = kt % 3;
        const int k0 = kt * 32;
        bf16x8 a[4], b[4];
#pragma unroll
        for (int i = 0; i < 4; ++i) {
            int mr = wm * 64 + i * 16 + lrow;
            int gx = (k0 >> 3) + (lane >> 4);
            a[i] = *(const bf16x8*)&H1[mr * 256 + ((gx ^ (mr & 7)) << 3)];
        }
#pragma unroll
        for (int j = 0; j < 4; ++j)
            b[j] = *(const bf16x8*)&Bs[buf][(wn * 64 + j * 16 + lrow) * 32 + lsw];
#pragma unroll
        for (int i = 0; i < 4; ++i)
#pragma unroll
            for (int j = 0; j < 4; ++j)
                acc[i][j] = __builtin_amdgcn_mfma_f32_16x16x32_bf16(a[i], b[j], acc[i][j], 0, 0, 0);
    }

    // ---- fc2 epilogue: scalar stores + shfl(16/32) stats ----
    float bv2[4], sv[4], qv[4];
#pragma unroll
    for (int j = 0; j < 4; ++j) {
        bv2[j] = bias2[wn * 64 + j * 16 + lrow];
        sv[j] = 0.f;
        qv[j] = 0.f;
    }
#pragma unroll
    for (int i = 0; i < 4; ++i) {
#pragma unroll
        for (int j = 0; j < 4; ++j) {
            int col = wn * 64 + j * 16 + lrow;
#pragma unroll
            for (int r = 0; r < 4; ++r) {
                int row = m0 + wm * 64 + i * 16 + (lane >> 4) * 4 + r;
                float v = elu(acc[i][j][r] + bv2[j]);
                sv[j] += v;
                qv[j] += v * v;
                out[(size_t)row * 256 + col] = f2bf(v);
            }
        }
    }
#pragma unroll
    for (int j = 0; j < 4; ++j) {
        float s = sv[j], q_ = qv[j];
        s += __shfl_xor(s, 16); q_ += __shfl_xor(q_, 16);
        s += __shfl_xor(s, 32); q_ += __shfl_xor(q_, 32);
        if ((lane >> 4) == 0) {
            int col = wn * 64 + j * 16 + lrow;
            atomicAdd(&stats[col], s);
            atomicAdd(&stats[256 + col], q_);
        }
    }
}

// ============================================================================
// mlp3_fused — r15 verbatim (verified).
// ============================================================================
__global__ __launch_bounds__(256) void mlp3_fused(const u16* __restrict__ A,
                                                  const u16* __restrict__ PB1,
                                                  const float* __restrict__ bias1,
                                                  const u16* __restrict__ PB2,
                                                  const float* __restrict__ bias2,
                                                  u16* __restrict__ out,
                                                  float* __restrict__ stats) {
    __shared__ u16 As[2][64 * 32];
    __shared__ u16 Bs[2][256 * 32];
    __shared__ u16 H1[64 * 256];

    const int tid = threadIdx.x;
    const int lane = tid & 63, wid = tid >> 6;
    int bid = blockIdx.x;
    int bm = (bid & 7) * 40 + (bid >> 3);
    const int m0 = bm * 64;
    const int wn = wid;

    const size_t ab = (size_t)(m0 + (tid >> 2)) * 256 + (tid & 3) * 8;

    const int lrow = lane & 15;
    const int lk8 = (lane >> 4) * 8;

    f32x4 acc[4][4];
#pragma unroll
    for (int i = 0; i < 4; ++i)
#pragma unroll
        for (int j = 0; j < 4; ++j) acc[i][j] = (f32x4)0.f;

    auto stage1 = [&](int bf, int k0) {
        GLL(A + ab + k0, &As[bf][tid * 8]);
        const u16* b_ = PB1 + (size_t)(k0 >> 5) * 8192;
#pragma unroll
        for (int q = 0; q < 4; ++q)
            GLL(b_ + (q * 256 + tid) * 8, &Bs[bf][(q * 256 + tid) * 8]);
    };
    auto stage2 = [&](int bf, int k0) {
        const u16* b_ = PB2 + (size_t)(k0 >> 5) * 8192;
#pragma unroll
        for (int q = 0; q < 4; ++q)
            GLL(b_ + (q * 256 + tid) * 8, &Bs[bf][(q * 256 + tid) * 8]);
    };

    stage1(0, 0);
    __syncthreads();
    for (int kt = 0; kt < 8; ++kt) {
        if (kt + 1 < 8) stage1((kt + 1) & 1, (kt + 1) * 32);
        const int buf = kt & 1;
        bf16x8 a[4], b[4];
#pragma unroll
        for (int i = 0; i < 4; ++i)
            a[i] = *(const bf16x8*)&As[buf][(i * 16 + lrow) * 32 + lk8];
#pragma unroll
        for (int j = 0; j < 4; ++j)
            b[j] = *(const bf16x8*)&Bs[buf][(wn * 64 + j * 16 + lrow) * 32 + lk8];
#pragma unroll
        for (int i = 0; i < 4; ++i)
#pragma unroll
            for (int j = 0; j < 4; ++j)
                acc[i][j] = __builtin_amdgcn_mfma_f32_16x16x32_bf16(a[i], b[j], acc[i][j], 0, 0, 0);
        __syncthreads();
    }

    stage2(0, 0);
    __builtin_amdgcn_sched_barrier(0);

#pragma unroll
    for (int j = 0; j < 4; ++j) {
        int c = wn * 64 + j * 16 + lrow;
        float bv = bias1[c];
        int gx = c >> 3;
        int cl = c & 7;
#pragma unroll
        for (int i = 0; i < 4; ++i) {
#pragma unroll
            for (int r = 0; r < 4; ++r) {
                int m = i * 16 + (lane >> 4) * 4 + r;
                float v = elu(acc[i][j][r] + bv);
                H1[m * 256 + ((gx ^ (m & 7)) << 3) + cl] = f2bf(v);
            }
        }
    }
    __syncthreads();

#pragma unroll
    for (int i = 0; i < 4; ++i)
#pragma unroll
        for (int j = 0; j < 4; ++j) acc[i][j] = (f32x4)0.f;

    for (int kt = 0; kt < 8; ++kt) {
        if (kt + 1 < 8) stage2((kt + 1) & 1, (kt + 1) * 32);
        const int buf = kt & 1;
        const int k0 = kt * 32;
        bf16x8 a[4], b[4];
#pragma unroll
        for (int i = 0; i < 4; ++i) {
            int mr = i * 16 + lrow;
            int gx = (k0 >> 3) + (lane >> 4);
            a[i] = *(const bf16x8*)&H1[mr * 256 + ((gx ^ (mr & 7)) << 3)];
        }
#pragma unroll
        for (int j = 0; j < 4; ++j)
            b[j] = *(const bf16x8*)&Bs[buf][(wn * 64 + j * 16 + lrow) * 32 + lk8];
#pragma unroll
        for (int i = 0; i < 4; ++i)
#pragma unroll
            for (int j = 0; j < 4; ++j)
                acc[i][j] = __builtin_amdgcn_mfma_f32_16x16x32_bf16(a[i], b[j], acc[i][j], 0, 0, 0);
        __syncthreads();
    }

    float bv2[4], sv[4], qv[4];
#pragma unroll
    for (int j = 0; j < 4; ++j) {
        bv2[j] = bias2[wn * 64 + j * 16 + lrow];
        sv[j] = 0.f;
        qv[j] = 0.f;
    }
#pragma unroll
    for (int i = 0; i < 4; ++i) {
#pragma unroll
        for (int j = 0; j < 4; ++j) {
            int col = wn * 64 + j * 16 + lrow;
#pragma unroll
            for (int r = 0; r < 4; ++r) {
                int row = m0 + i * 16 + (lane >> 4) * 4 + r;
                float v = elu(acc[i][j][r] + bv2[j]);
                sv[j] += v;
                qv[j] += v * v;
                out[(size_t)row * 256 + col] = f2bf(v);
            }
        }
    }
#pragma unroll
    for (int j = 0; j < 4; ++j) {
        float s = sv[j], q_ = qv[j];
        s += __shfl_xor(s, 16); q_ += __shfl_xor(q_, 16);
        s += __shfl_xor(s, 32); q_ += __shfl_xor(q_, 32);
        if ((lane >> 4) == 0) {
            int col = wn * 64 + j * 16 + lrow;
            atomicAdd(&stats[col], s);
            atomicAdd(&stats[256 + col], q_);
        }
    }
}

// ============================================================================
// head_fused — r15 verbatim (verified).
// ============================================================================
__global__ __launch_bounds__(256) void head_fused(const u16* __restrict__ A,
                                                  const u16* __restrict__ PB1,
                                                  const float* __restrict__ bo1,
                                                  const float* __restrict__ wo2,
                                                  const float* __restrict__ bo2,
                                                  float* __restrict__ out) {
    __shared__ u16 As[2][64 * 32];
    __shared__ u16 Bs[2][256 * 32];
    __shared__ float rs[64 * 4];

    const int tid = threadIdx.x;
    const int lane = tid & 63, wid = tid >> 6;
    int bid = blockIdx.x;
    int bm = (bid & 7) * 40 + (bid >> 3);
    const int m0 = bm * 64;
    const int wn = wid;

    const size_t ab = (size_t)(m0 + (tid >> 2)) * 256 + (tid & 3) * 8;

    const int lrow = lane & 15;
    const int lk8 = (lane >> 4) * 8;

    f32x4 acc[4][4];
#pragma unroll
    for (int i = 0; i < 4; ++i)
#pragma unroll
        for (int j = 0; j < 4; ++j) acc[i][j] = (f32x4)0.f;

    auto stage1 = [&](int bf, int k0) {
        GLL(A + ab + k0, &As[bf][tid * 8]);
        const u16* b_ = PB1 + (size_t)(k0 >> 5) * 8192;
#pragma unroll
        for (int q = 0; q < 4; ++q)
            GLL(b_ + (q * 256 + tid) * 8, &Bs[bf][(q * 256 + tid) * 8]);
    };

    stage1(0, 0);
    __syncthreads();
    for (int kt = 0; kt < 8; ++kt) {
        if (kt + 1 < 8) stage1((kt + 1) & 1, (kt + 1) * 32);
        const int buf = kt & 1;
        bf16x8 a[4], b[4];
#pragma unroll
        for (int i = 0; i < 4; ++i)
            a[i] = *(const bf16x8*)&As[buf][(i * 16 + lrow) * 32 + lk8];
#pragma unroll
        for (int j = 0; j < 4; ++j)
            b[j] = *(const bf16x8*)&Bs[buf][(wn * 64 + j * 16 + lrow) * 32 + lk8];
#pragma unroll
        for (int i = 0; i < 4; ++i)
#pragma unroll
            for (int j = 0; j < 4; ++j)
                acc[i][j] = __builtin_amdgcn_mfma_f32_16x16x32_bf16(a[i], b[j], acc[i][j], 0, 0, 0);
        __syncthreads();
    }

    float p[4][4];
#pragma unroll
    for (int i = 0; i < 4; ++i)
#pragma unroll
        for (int r = 0; r < 4; ++r) p[i][r] = 0.f;
#pragma unroll
    for (int j = 0; j < 4; ++j) {
        int col = wn * 64 + j * 16 + lrow;
        float bv = bo1[col];
        float w = wo2[col];
#pragma unroll
        for (int i = 0; i < 4; ++i) {
#pragma unroll
            for (int r = 0; r < 4; ++r) {
                float v = acc[i][j][r] + bv;
                v = v > 0.f ? v : 0.f;
                p[i][r] += v * w;
            }
        }
    }
#pragma unroll
    for (int i = 0; i < 4; ++i) {
#pragma unroll
        for (int r = 0; r < 4; ++r) {
            float s = p[i][r];
            s += __shfl_xor(s, 1);
            s += __shfl_xor(s, 2);
            s += __shfl_xor(s, 4);
            s += __shfl_xor(s, 8);
            p[i][r] = s;
        }
    }
    if (lrow == 0) {
#pragma unroll
        for (int i = 0; i < 4; ++i)
#pragma unroll
            for (int r = 0; r < 4; ++r) {
                int rowlocal = i * 16 + (lane >> 4) * 4 + r;
                rs[rowlocal * 4 + wn] = p[i][r];
            }
    }
    __syncthreads();
    if (tid < 64) {
        float s = rs[tid * 4] + rs[tid * 4 + 1] + rs[tid * 4 + 2] + rs[tid * 4 + 3] + bo2[0];
        int m = m0 + tid;
        int b = m / (NV * TT);
        int v = (m >> 6) % NV;
        int t = m & 63;
        out[(size_t)(b * TT + t) * NV + v] = s;
    }
}

// -------------------- BN3 affine + relu (scsh computed inline) ---------------
__global__ __launch_bounds__(256) void norm_affine_relu(const u16* __restrict__ in,
                                                        const float* __restrict__ sums,
                                                        const float* __restrict__ g3,
                                                        const float* __restrict__ be3,
                                                        u16* __restrict__ out, int n8) {
    int i = blockIdx.x * 256 + threadIdx.x;
    if (i >= n8) return;
    size_t base = (size_t)i * 8;
    int ch8 = (int)(base & 255);
    u16x8 v = *(const u16x8*)(in + base);
    u16x8 o;
#pragma unroll
    for (int e = 0; e < 8; ++e) {
        int c = ch8 + e;
        float mu = sums[c] * INV_R1;
        float var = sums[256 + c] * INV_R1 - mu * mu;
        float sc = g3[c] * rsqrtf(var + 1e-5f);
        float sh = be3[c] - mu * sc;
        float f = bf2f(v[e]) * sc + sh;
        o[e] = f2bf(f > 0.f ? f : 0.f);
    }
    *(u16x8*)(out + base) = o;
}

// -------------------- edge2node: incidence sum + BN2 affine (inline scsh) ----
__global__ __launch_bounds__(256) void edge2node(const u16* __restrict__ h2,
                                                 const float* __restrict__ sums,
                                                 const float* __restrict__ g2,
                                                 const float* __restrict__ be2,
                                                 u16* __restrict__ n1) {
    int tid = threadIdx.x;
    int row = blockIdx.x * 8 + (tid >> 5);
    int ch8 = (tid & 31) * 8;
    int t = row & 63;
    int bv = row >> 6;
    int v = bv % NV;
    int b = bv / NV;
    float acc[8] = {0, 0, 0, 0, 0, 0, 0, 0};
#pragma unroll
    for (int i = 0; i < 9; ++i) {
        int s = i + (i >= v ? 1 : 0);
        int e = s * 9 + (v < s ? v : v - 1);
        u16x8 vv = *(const u16x8*)(h2 + ((size_t)((b * NE + e) * TT + t)) * 256 + ch8);
#pragma unroll
        for (int k = 0; k < 8; ++k) acc[k] += bf2f(vv[k]);
    }
    const float inv9 = 1.f / 9.f;
    u16x8 o;
#pragma unroll
    for (int k = 0; k < 8; ++k) {
        int c = ch8 + k;
        float mu = sums[c] * INV_R2;
        float var = sums[256 + c] * INV_R2 - mu * mu;
        float sc = g2[c] * rsqrtf(var + 1e-5f);
        float sh = be2[c] - mu * sc;
        o[k] = f2bf(sc * (acc[k] * inv9) + sh);
    }
    *(u16x8*)(n1 + (size_t)row * 256 + ch8) = o;
}

extern "C" void kernel_launch(void* const* d_in, const int* in_sizes, int n_in,
                              void* d_out, int out_size, void* d_ws, size_t ws_size,
                              hipStream_t stream) {
    const float* x   = (const float*)d_in[0];
    const float* w1a = (const float*)d_in[1];
    const float* b1a = (const float*)d_in[2];
    const float* w1b = (const float*)d_in[3];
    const float* b1b = (const float*)d_in[4];
    const float* g1  = (const float*)d_in[5];
    const float* be1 = (const float*)d_in[6];
    const float* w2a = (const float*)d_in[7];
    const float* b2a = (const float*)d_in[8];
    const float* w2b = (const float*)d_in[9];
    const float* b2b = (const float*)d_in[10];
    const float* g2  = (const float*)d_in[11];
    const float* be2 = (const float*)d_in[12];
    const float* w3a = (const float*)d_in[13];
    const float* b3a = (const float*)d_in[14];
    const float* w3b = (const float*)d_in[15];
    const float* b3b = (const float*)d_in[16];
    const float* g3  = (const float*)d_in[17];
    const float* be3 = (const float*)d_in[18];
    const float* wo1 = (const float*)d_in[19];
    const float* bo1 = (const float*)d_in[20];
    const float* wo2 = (const float*)d_in[21];
    const float* bo2 = (const float*)d_in[22];
    float* out = (float*)d_out;

    char* ws = (char*)d_ws;
    size_t off = 0;
    auto alloc = [&](size_t bytes) {
        void* p = ws + off;
        off = (off + bytes + 255) & ~(size_t)255;
        return p;
    };
    u16* w1bP = (u16*)alloc(2 * 8 * 4096 * 2);
    u16* w3aP = (u16*)alloc(8 * 8192 * 2);
    u16* w3bP = (u16*)alloc(8 * 8192 * 2);
    u16* wo1P = (u16*)alloc(8 * 8192 * 2);
    u16* w2aP = (u16*)alloc(16 * 8192 * 2);
    u16* w2bP = (u16*)alloc(8 * 8192 * 2);
    float* sums  = (float*)alloc(3 * 512 * 4);
    float* b2aF  = (float*)alloc(256 * 4);
    u16* S0 = (u16*)alloc((size_t)R1 * 256 * 2);
    u16* S1 = (u16*)alloc((size_t)R1 * 256 * 2);
    u16* S2 = (u16*)alloc((size_t)R1 * 256 * 2);
    u16* BIG2 = (u16*)alloc((size_t)R2 * 256 * 2);

    pack128<<<16, 256, 0, stream>>>(w1b, w1bP);
    dim3 p3grid(8, 3);
    pack256_3<<<p3grid, 256, 0, stream>>>(w3a, w3aP, w3b, w3bP, wo1, wo1P);
    pack256s<<<8, 256, 0, stream>>>(w2b, w2bP);
    zero_stats<<<6, 256, 0, stream>>>(sums, 3 * 512);

    // mlp1: fc1 (VALU) + fc2 GEMM with fused stats
    mlp1_fc1<<<R1 / 8, 256, 0, stream>>>(x, w1a, b1a, S0);
    gemm_kernel<1, true><<<(R1 / 128) * 2, 256, 0, stream>>>(S0, w1bP, b1b, S1, 256, sums);
    pack256s_w2a<<<16, 256, 0, stream>>>(w2a, sums, g1, w2aP);
    fold_b2a<<<256, 256, 0, stream>>>(w2a, sums, g1, be1, b2a, b2aF);

    // mlp2: fused gather-fc1 + fc2 (r15-verified 512-thread engine)
    mlp2_fused<<<R2 / 128, 512, 0, stream>>>(S1, w2aP, b2aF, w2bP, b2b, BIG2, sums + 512);

    // edge2node (BN2 affine computed inline from sums)
    edge2node<<<R1 / 8, 256, 0, stream>>>(BIG2, sums + 512, g2, be2, S0);

    // mlp3: fused fc1+fc2, stats fused
    mlp3_fused<<<R1 / 64, 256, 0, stream>>>(S0, w3aP, b3a, w3bP, b3b, S2, sums + 1024);

    // head: BN3 affine+relu (inline scsh), then fused wo1 GEMM + dot wo2
    norm_affine_relu<<<(R1 * 32 + 255) / 256, 256, 0, stream>>>(S2, sums + 1024, g3, be3, S0, R1 * 32);
    head_fused<<<R1 / 64, 256, 0, stream>>>(S0, wo1P, bo1, wo2, bo2, out);
}

// Round 18
// 227.480 us; speedup vs baseline: 1.2855x; 1.0493x over previous
//
#include <hip/hip_runtime.h>
#include <hip/hip_bf16.h>
#include <cstdint>

#define DI __device__ __forceinline__

typedef short bf16x8 __attribute__((ext_vector_type(8)));
typedef float f32x4 __attribute__((ext_vector_type(4)));
typedef unsigned short u16;
typedef unsigned short u16x8 __attribute__((ext_vector_type(8)));

static constexpr int NV = 10, NE = 90, TT = 64;
static constexpr int R1 = 20480;   // 32*10*64 node rows
static constexpr int R2 = 184320;  // 32*90*64 edge rows
static constexpr float INV_R1 = 1.f / 20480.f;
static constexpr float INV_R2 = 1.f / 184320.f;
static constexpr int H1S = 264;    // padded H1 row stride (u16): 528B = 16B-aligned,
                                   // row-to-row bank start shifts 4 dwords -> no swizzle needed

DI float bf2f(u16 u) { union { unsigned int i; float f; } x; x.i = ((unsigned int)u) << 16; return x.f; }
DI u16 f2bf(float f) { unsigned int u = __float_as_uint(f); return (u16)((u + 0x7FFF + ((u >> 16) & 1)) >> 16); }
DI float elu(float v) { return v > 0.f ? v : __expf(v) - 1.f; }

#define GLL(srcp, dstp) __builtin_amdgcn_global_load_lds( \
    (const __attribute__((address_space(1))) unsigned int*)(srcp), \
    (__attribute__((address_space(3))) unsigned int*)(dstp), 16, 0, 0)

// ============================================================================
// 128-tile weight packing (mlp1-fc2 gemm, r8-verified)
// ============================================================================
__global__ __launch_bounds__(256) void pack128(const float* __restrict__ s,
                                               u16* __restrict__ d) {
    int tid = threadIdx.x;
    int bn = blockIdx.x >> 3, kt = blockIdx.x & 7;
#pragma unroll
    for (int p = 0; p < 2; ++p) {
        int n = bn * 128 + p * 64 + (tid >> 2);
        int k = kt * 32 + (tid & 3) * 8;
        u16x8 pk;
#pragma unroll
        for (int e = 0; e < 8; ++e) pk[e] = f2bf(s[(size_t)(k + e) * 256 + n]);
        *(u16x8*)(d + ((size_t)((bn * 8 + kt) * 2 + p)) * 2048 + (size_t)tid * 8) = pk;
    }
}

// ============================================================================
// 256-wide NON-swizzled packs (r13-verified layout) for mlp3/head fused
// ============================================================================
__global__ __launch_bounds__(256) void pack256_3(
    const float* __restrict__ s0, u16* __restrict__ d0,
    const float* __restrict__ s1, u16* __restrict__ d1,
    const float* __restrict__ s2, u16* __restrict__ d2) {
    const float* s; u16* d;
    switch (blockIdx.y) {
        case 0: s = s0; d = d0; break;
        case 1: s = s1; d = d1; break;
        default: s = s2; d = d2; break;
    }
    int kt = blockIdx.x;
#pragma unroll
    for (int h = 0; h < 4; ++h) {
        int tid2 = threadIdx.x + h * 256;
        int n = tid2 >> 2;
        int k = kt * 32 + (tid2 & 3) * 8;
        u16x8 pk;
#pragma unroll
        for (int e = 0; e < 8; ++e) pk[e] = f2bf(s[(size_t)(k + e) * 256 + n]);
        *(u16x8*)(d + (size_t)kt * 8192 + (size_t)tid2 * 8) = pk;
    }
}

// ============================================================================
// SWIZZLED 256-wide packs for mlp2_fused (r14/r15-verified): granule position
// p of row n holds k-chunk p^(n&3)
// ============================================================================
__global__ __launch_bounds__(256) void pack256s(const float* __restrict__ s,
                                                u16* __restrict__ d) {
    int kt = blockIdx.x;
#pragma unroll
    for (int h = 0; h < 4; ++h) {
        int tid2 = threadIdx.x + h * 256;
        int n = tid2 >> 2;
        int g = (tid2 & 3) ^ ((tid2 >> 2) & 3);
        int k = kt * 32 + g * 8;
        u16x8 pk;
#pragma unroll
        for (int e = 0; e < 8; ++e) pk[e] = f2bf(s[(size_t)(k + e) * 256 + n]);
        *(u16x8*)(d + (size_t)kt * 8192 + (size_t)tid2 * 8) = pk;
    }
}

// w2a swizzled pack, K=512, BN1 scale folded (scsh1 computed INLINE from sums)
__global__ __launch_bounds__(256) void pack256s_w2a(const float* __restrict__ w2a,
                                                    const float* __restrict__ sums,
                                                    const float* __restrict__ g1,
                                                    u16* __restrict__ d) {
    int kt = blockIdx.x;
#pragma unroll
    for (int h = 0; h < 4; ++h) {
        int tid2 = threadIdx.x + h * 256;
        int n = tid2 >> 2;
        int g = (tid2 & 3) ^ ((tid2 >> 2) & 3);
        int k = kt * 32 + g * 8;
        u16x8 pk;
#pragma unroll
        for (int e = 0; e < 8; ++e) {
            int c = (k + e) & 255;
            float mu = sums[c] * INV_R1;
            float var = sums[256 + c] * INV_R1 - mu * mu;
            float sc = g1[c] * rsqrtf(var + 1e-5f);
            pk[e] = f2bf(sc * w2a[(size_t)(k + e) * 256 + n]);
        }
        *(u16x8*)(d + (size_t)kt * 8192 + (size_t)tid2 * 8) = pk;
    }
}

__global__ void zero_stats(float* p, int n) {
    int i = blockIdx.x * 256 + threadIdx.x;
    if (i < n) p[i] = 0.f;
}

// BN1 shift term folded into fc1 bias (shift computed INLINE from sums)
__global__ __launch_bounds__(256) void fold_b2a(const float* __restrict__ w2a,
                                                const float* __restrict__ sums,
                                                const float* __restrict__ g1,
                                                const float* __restrict__ be1,
                                                const float* __restrict__ b2a,
                                                float* __restrict__ b2aF) {
    __shared__ float red[256];
    int n = blockIdx.x, tid = threadIdx.x;
    float mu = sums[tid] * INV_R1;
    float var = sums[256 + tid] * INV_R1 - mu * mu;
    float sc = g1[tid] * rsqrtf(var + 1e-5f);
    float sh = be1[tid] - mu * sc;
    float s = sh * w2a[tid * 256 + n] + sh * w2a[(tid + 256) * 256 + n];
    red[tid] = s;
    __syncthreads();
    for (int off2 = 128; off2 > 0; off2 >>= 1) {
        if (tid < off2) red[tid] += red[tid + off2];
        __syncthreads();
    }
    if (tid == 0) b2aF[n] = red[0] + b2a[n];
}

// -------------------- mlp1 fc1: K=4, VALU (verified) -------------------------
__global__ __launch_bounds__(256) void mlp1_fc1(const float* __restrict__ x,
                                                const float* __restrict__ w1a,
                                                const float* __restrict__ b1a,
                                                u16* __restrict__ ha) {
    int tid = threadIdx.x;
    int row = blockIdx.x * 8 + (tid >> 5);
    int ch8 = (tid & 31) * 8;
    int b = row / (NV * TT);
    int v = (row >> 6) % NV;
    int t = row & 63;
    const float* xp = x + ((size_t)(b * TT + t) * NV + v) * 4;
    float x0 = xp[0], x1 = xp[1], x2 = xp[2], x3 = xp[3];
    u16x8 pack;
#pragma unroll
    for (int e = 0; e < 8; ++e) {
        int c = ch8 + e;
        float acc = b1a[c] + x0 * w1a[c] + x1 * w1a[256 + c] + x2 * w1a[512 + c] + x3 * w1a[768 + c];
        pack[e] = f2bf(elu(acc));
    }
    *(u16x8*)(ha + (size_t)row * 256 + ch8) = pack;
}

// ============================================================================
// 128x128 engine (r8-verified, packed-B) — mlp1 fc2. UNCHANGED.
// ============================================================================
template <int ACT, bool STATS>
__global__ __launch_bounds__(256) void gemm_kernel(const u16* __restrict__ A,
                                                   const u16* __restrict__ Wt,
                                                   const float* __restrict__ bias,
                                                   u16* __restrict__ out,
                                                   int K,
                                                   float* __restrict__ stats) {
    __shared__ u16 As[3][128 * 32];
    __shared__ u16 Bs[3][128 * 32];
    const int tid = threadIdx.x;
    const int lane = tid & 63, wid = tid >> 6;

    int bm, bn;
    {
        int bid = blockIdx.x;
        int xcd = bid & 7, slot = bid >> 3;
        bn = slot & 1;
        bm = xcd + 8 * (slot >> 1);
    }
    const int m0 = bm * 128, n0 = bn * 128;
    const int wm = wid >> 1, wn = wid & 1;

    const int srow = tid >> 2;
    const int scol8 = (tid & 3) * 8;

    size_t abase0 = (size_t)(m0 + srow) * K;
    size_t abase1 = (size_t)(m0 + srow + 64) * K;
    const int NT = K >> 5;
    const size_t bnbase = (size_t)bn * NT * 4096;

    f32x4 acc[4][4];
#pragma unroll
    for (int i = 0; i < 4; ++i)
#pragma unroll
        for (int j = 0; j < 4; ++j) acc[i][j] = (f32x4)0.f;

    const int lrow = lane & 15;
    const int lk8 = (lane >> 4) * 8;

    auto stage = [&](int bf, int k0) {
        const size_t btile = bnbase + (size_t)(k0 >> 5) * 4096 + (size_t)tid * 8;
        GLL(A + abase0 + k0 + scol8, &As[bf][(wid * 64) * 8]);
        GLL(Wt + btile, &Bs[bf][(wid * 64) * 8]);
        GLL(A + abase1 + k0 + scol8, &As[bf][(256 + wid * 64) * 8]);
        GLL(Wt + btile + 2048, &Bs[bf][(256 + wid * 64) * 8]);
    };

    stage(0, 0);
    stage(1, 32);
    for (int kt = 0; kt < NT; ++kt) {
        if (kt + 1 < NT) {
            asm volatile("s_waitcnt vmcnt(4)" ::: "memory");
        } else {
            asm volatile("s_waitcnt vmcnt(0)" ::: "memory");
        }
        __builtin_amdgcn_s_barrier();
        if (kt + 2 < NT) stage((kt + 2) % 3, (kt + 2) * 32);
        __builtin_amdgcn_sched_barrier(0);
        const int buf = kt % 3;
        bf16x8 a[4], b[4];
#pragma unroll
        for (int i = 0; i < 4; ++i)
            a[i] = *(const bf16x8*)&As[buf][(wm * 64 + i * 16 + lrow) * 32 + lk8];
#pragma unroll
        for (int j = 0; j < 4; ++j)
            b[j] = *(const bf16x8*)&Bs[buf][(wn * 64 + j * 16 + lrow) * 32 + lk8];
#pragma unroll
        for (int i = 0; i < 4; ++i)
#pragma unroll
            for (int j = 0; j < 4; ++j)
                acc[i][j] = __builtin_amdgcn_mfma_f32_16x16x32_bf16(a[i], b[j], acc[i][j], 0, 0, 0);
    }

    float bv[4], sv[4], qv[4];
#pragma unroll
    for (int j = 0; j < 4; ++j) {
        bv[j] = bias[n0 + wn * 64 + j * 16 + lrow];
        if constexpr (STATS) { sv[j] = 0.f; qv[j] = 0.f; }
    }
#pragma unroll
    for (int i = 0; i < 4; ++i) {
#pragma unroll
        for (int j = 0; j < 4; ++j) {
            int col = n0 + wn * 64 + j * 16 + lrow;
#pragma unroll
            for (int r = 0; r < 4; ++r) {
                int row = m0 + wm * 64 + i * 16 + (lane >> 4) * 4 + r;
                float v = acc[i][j][r] + bv[j];
                v = (ACT == 1) ? elu(v) : (v > 0.f ? v : 0.f);
                if constexpr (STATS) { sv[j] += v; qv[j] += v * v; }
                out[(size_t)row * 256 + col] = f2bf(v);
            }
        }
    }
    if constexpr (STATS) {
#pragma unroll
        for (int j = 0; j < 4; ++j) {
            float s = sv[j], q_ = qv[j];
            s += __shfl_xor(s, 16); q_ += __shfl_xor(q_, 16);
            s += __shfl_xor(s, 32); q_ += __shfl_xor(q_, 32);
            if ((lane >> 4) == 0) {
                int col = n0 + wn * 64 + j * 16 + lrow;
                atomicAdd(&stats[col], s);
                atomicAdd(&stats[256 + col], q_);
            }
        }
    }
}

// ============================================================================
// mlp2_fused — r15/r17 structure with PADDED H1 (stride 264 u16, no swizzle):
// row-to-row bank start shifts 4 dwords so fc1-epilogue scalar writes spread
// all 32 banks (was: groups m/m+8 colliding at stride-512B) and fc2 b128
// A-reads start at distinct banks per row. Only H1 addressing changed.
// ============================================================================
__global__ __launch_bounds__(512) void mlp2_fused(const u16* __restrict__ A,
                                                  const u16* __restrict__ PB1,
                                                  const float* __restrict__ bias1,
                                                  const u16* __restrict__ PB2,
                                                  const float* __restrict__ bias2,
                                                  u16* __restrict__ out,
                                                  float* __restrict__ stats) {
    __shared__ u16 As[3][128 * 32];    // 24 KB
    __shared__ u16 Bs[3][256 * 32];    // 48 KB
    __shared__ u16 H1[128 * H1S];      // 66 KB (padded)

    const int tid = threadIdx.x;
    const int lane = tid & 63, wid = tid >> 6;     // 8 waves

    int bid = blockIdx.x;
    int xcd = bid & 7, slot = bid >> 3;            // 1440 = 8*180
    int batch = xcd + 8 * (slot / 45);
    int bm = batch * 45 + (slot % 45);
    const int m0 = bm * 128;
    const int wm = wid >> 2, wn = wid & 3;          // 2M x 4N wave grid

    size_t sb, rb;
    {
        int m = m0 + (tid >> 2);
        int t = m & 63, be = m >> 6, e = be % NE, b = be / NE;
        int s = e / 9, kk = e - s * 9, r = kk + (kk >= s ? 1 : 0);
        int achk = (tid & 3) ^ ((tid >> 2) & 3);
        sb = ((size_t)((b * NV + s) * TT + t)) * 256 + achk * 8;
        rb = ((size_t)((b * NV + r) * TT + t)) * 256 + achk * 8;
    }

    const int lrow = lane & 15;
    const int lsw = (((lane >> 4) ^ (lrow & 3))) * 8;
    const int lk8 = (lane >> 4) * 8;

    f32x4 acc[4][4];
#pragma unroll
    for (int i = 0; i < 4; ++i)
#pragma unroll
        for (int j = 0; j < 4; ++j) acc[i][j] = (f32x4)0.f;

    auto stage1 = [&](int bf, int k0) {
        GLL(A + (k0 < 256 ? sb : rb) + (k0 & 255), &As[bf][tid * 8]);
        const u16* b_ = PB1 + (size_t)(k0 >> 5) * 8192 + (size_t)tid * 8;
        GLL(b_, &Bs[bf][tid * 8]);
        GLL(b_ + 4096, &Bs[bf][4096 + tid * 8]);
    };
    auto stage2 = [&](int bf, int k0) {
        const u16* b_ = PB2 + (size_t)(k0 >> 5) * 8192 + (size_t)tid * 8;
        GLL(b_, &Bs[bf][tid * 8]);
        GLL(b_ + 4096, &Bs[bf][4096 + tid * 8]);
    };

    // ---------------- fc1: K=512, NT=16 ----------------
    stage1(0, 0);
    stage1(1, 32);
    for (int kt = 0; kt < 16; ++kt) {
        if (kt + 1 < 16) {
            asm volatile("s_waitcnt vmcnt(3)" ::: "memory");
        } else {
            asm volatile("s_waitcnt vmcnt(0)" ::: "memory");
        }
        __builtin_amdgcn_s_barrier();
        if (kt + 2 < 16) stage1((kt + 2) % 3, (kt + 2) * 32);
        __builtin_amdgcn_sched_barrier(0);
        const int buf = kt % 3;
        bf16x8 a[4], b[4];
#pragma unroll
        for (int i = 0; i < 4; ++i)
            a[i] = *(const bf16x8*)&As[buf][(wm * 64 + i * 16 + lrow) * 32 + lsw];
#pragma unroll
        for (int j = 0; j < 4; ++j)
            b[j] = *(const bf16x8*)&Bs[buf][(wn * 64 + j * 16 + lrow) * 32 + lsw];
#pragma unroll
        for (int i = 0; i < 4; ++i)
#pragma unroll
            for (int j = 0; j < 4; ++j)
                acc[i][j] = __builtin_amdgcn_mfma_f32_16x16x32_bf16(a[i], b[j], acc[i][j], 0, 0, 0);
    }

    // publish; issue fc2's first B-stages so GLL latency hides under epilogue
    __builtin_amdgcn_s_barrier();
    stage2(0, 0);
    stage2(1, 32);
    __builtin_amdgcn_sched_barrier(0);

    // ---- fc1 epilogue -> H1 (plain padded writes, conflict-free) ----
#pragma unroll
    for (int j = 0; j < 4; ++j) {
        int c = wn * 64 + j * 16 + lrow;
        float bv = bias1[c];
#pragma unroll
        for (int i = 0; i < 4; ++i) {
#pragma unroll
            for (int r = 0; r < 4; ++r) {
                int m = wm * 64 + i * 16 + (lane >> 4) * 4 + r;
                float v = elu(acc[i][j][r] + bv);
                H1[m * H1S + c] = f2bf(v);
            }
        }
    }
    __syncthreads();

    // ---------------- fc2: K=256, NT=8, A from H1 (padded plain reads) ------
#pragma unroll
    for (int i = 0; i < 4; ++i)
#pragma unroll
        for (int j = 0; j < 4; ++j) acc[i][j] = (f32x4)0.f;

    for (int kt = 0; kt < 8; ++kt) {
        if (kt + 1 < 8) {
            asm volatile("s_waitcnt vmcnt(2)" ::: "memory");
        } else {
            asm volatile("s_waitcnt vmcnt(0)" ::: "memory");
        }
        __builtin_amdgcn_s_barrier();
        if (kt + 2 < 8) stage2((kt + 2) % 3, (kt + 2) * 32);
        __builtin_amdgcn_sched_barrier(0);
        const int buf = kt % 3;
        const int k0 = kt * 32;
        bf16x8 a[4], b[4];
#pragma unroll
        for (int i = 0; i < 4; ++i) {
            int mr = wm * 64 + i * 16 + lrow;
            a[i] = *(const bf16x8*)&H1[mr * H1S + k0 + lk8];
        }
#pragma unroll
        for (int j = 0; j < 4; ++j)
            b[j] = *(const bf16x8*)&Bs[buf][(wn * 64 + j * 16 + lrow) * 32 + lsw];
#pragma unroll
        for (int i = 0; i < 4; ++i)
#pragma unroll
            for (int j = 0; j < 4; ++j)
                acc[i][j] = __builtin_amdgcn_mfma_f32_16x16x32_bf16(a[i], b[j], acc[i][j], 0, 0, 0);
    }

    // ---- fc2 epilogue: scalar stores + shfl(16/32) stats ----
    float bv2[4], sv[4], qv[4];
#pragma unroll
    for (int j = 0; j < 4; ++j) {
        bv2[j] = bias2[wn * 64 + j * 16 + lrow];
        sv[j] = 0.f;
        qv[j] = 0.f;
    }
#pragma unroll
    for (int i = 0; i < 4; ++i) {
#pragma unroll
        for (int j = 0; j < 4; ++j) {
            int col = wn * 64 + j * 16 + lrow;
#pragma unroll
            for (int r = 0; r < 4; ++r) {
                int row = m0 + wm * 64 + i * 16 + (lane >> 4) * 4 + r;
                float v = elu(acc[i][j][r] + bv2[j]);
                sv[j] += v;
                qv[j] += v * v;
                out[(size_t)row * 256 + col] = f2bf(v);
            }
        }
    }
#pragma unroll
    for (int j = 0; j < 4; ++j) {
        float s = sv[j], q_ = qv[j];
        s += __shfl_xor(s, 16); q_ += __shfl_xor(q_, 16);
        s += __shfl_xor(s, 32); q_ += __shfl_xor(q_, 32);
        if ((lane >> 4) == 0) {
            int col = wn * 64 + j * 16 + lrow;
            atomicAdd(&stats[col], s);
            atomicAdd(&stats[256 + col], q_);
        }
    }
}

// ============================================================================
// mlp3_fused — r15 structure with PADDED H1 (stride 264, no swizzle).
// ============================================================================
__global__ __launch_bounds__(256) void mlp3_fused(const u16* __restrict__ A,
                                                  const u16* __restrict__ PB1,
                                                  const float* __restrict__ bias1,
                                                  const u16* __restrict__ PB2,
                                                  const float* __restrict__ bias2,
                                                  u16* __restrict__ out,
                                                  float* __restrict__ stats) {
    __shared__ u16 As[2][64 * 32];
    __shared__ u16 Bs[2][256 * 32];
    __shared__ u16 H1[64 * H1S];

    const int tid = threadIdx.x;
    const int lane = tid & 63, wid = tid >> 6;
    int bid = blockIdx.x;
    int bm = (bid & 7) * 40 + (bid >> 3);
    const int m0 = bm * 64;
    const int wn = wid;

    const size_t ab = (size_t)(m0 + (tid >> 2)) * 256 + (tid & 3) * 8;

    const int lrow = lane & 15;
    const int lk8 = (lane >> 4) * 8;

    f32x4 acc[4][4];
#pragma unroll
    for (int i = 0; i < 4; ++i)
#pragma unroll
        for (int j = 0; j < 4; ++j) acc[i][j] = (f32x4)0.f;

    auto stage1 = [&](int bf, int k0) {
        GLL(A + ab + k0, &As[bf][tid * 8]);
        const u16* b_ = PB1 + (size_t)(k0 >> 5) * 8192;
#pragma unroll
        for (int q = 0; q < 4; ++q)
            GLL(b_ + (q * 256 + tid) * 8, &Bs[bf][(q * 256 + tid) * 8]);
    };
    auto stage2 = [&](int bf, int k0) {
        const u16* b_ = PB2 + (size_t)(k0 >> 5) * 8192;
#pragma unroll
        for (int q = 0; q < 4; ++q)
            GLL(b_ + (q * 256 + tid) * 8, &Bs[bf][(q * 256 + tid) * 8]);
    };

    stage1(0, 0);
    __syncthreads();
    for (int kt = 0; kt < 8; ++kt) {
        if (kt + 1 < 8) stage1((kt + 1) & 1, (kt + 1) * 32);
        const int buf = kt & 1;
        bf16x8 a[4], b[4];
#pragma unroll
        for (int i = 0; i < 4; ++i)
            a[i] = *(const bf16x8*)&As[buf][(i * 16 + lrow) * 32 + lk8];
#pragma unroll
        for (int j = 0; j < 4; ++j)
            b[j] = *(const bf16x8*)&Bs[buf][(wn * 64 + j * 16 + lrow) * 32 + lk8];
#pragma unroll
        for (int i = 0; i < 4; ++i)
#pragma unroll
            for (int j = 0; j < 4; ++j)
                acc[i][j] = __builtin_amdgcn_mfma_f32_16x16x32_bf16(a[i], b[j], acc[i][j], 0, 0, 0);
        __syncthreads();
    }

    stage2(0, 0);
    __builtin_amdgcn_sched_barrier(0);

#pragma unroll
    for (int j = 0; j < 4; ++j) {
        int c = wn * 64 + j * 16 + lrow;
        float bv = bias1[c];
#pragma unroll
        for (int i = 0; i < 4; ++i) {
#pragma unroll
            for (int r = 0; r < 4; ++r) {
                int m = i * 16 + (lane >> 4) * 4 + r;
                float v = elu(acc[i][j][r] + bv);
                H1[m * H1S + c] = f2bf(v);
            }
        }
    }
    __syncthreads();

#pragma unroll
    for (int i = 0; i < 4; ++i)
#pragma unroll
        for (int j = 0; j < 4; ++j) acc[i][j] = (f32x4)0.f;

    for (int kt = 0; kt < 8; ++kt) {
        if (kt + 1 < 8) stage2((kt + 1) & 1, (kt + 1) * 32);
        const int buf = kt & 1;
        const int k0 = kt * 32;
        bf16x8 a[4], b[4];
#pragma unroll
        for (int i = 0; i < 4; ++i) {
            int mr = i * 16 + lrow;
            a[i] = *(const bf16x8*)&H1[mr * H1S + k0 + lk8];
        }
#pragma unroll
        for (int j = 0; j < 4; ++j)
            b[j] = *(const bf16x8*)&Bs[buf][(wn * 64 + j * 16 + lrow) * 32 + lk8];
#pragma unroll
        for (int i = 0; i < 4; ++i)
#pragma unroll
            for (int j = 0; j < 4; ++j)
                acc[i][j] = __builtin_amdgcn_mfma_f32_16x16x32_bf16(a[i], b[j], acc[i][j], 0, 0, 0);
        __syncthreads();
    }

    float bv2[4], sv[4], qv[4];
#pragma unroll
    for (int j = 0; j < 4; ++j) {
        bv2[j] = bias2[wn * 64 + j * 16 + lrow];
        sv[j] = 0.f;
        qv[j] = 0.f;
    }
#pragma unroll
    for (int i = 0; i < 4; ++i) {
#pragma unroll
        for (int j = 0; j < 4; ++j) {
            int col = wn * 64 + j * 16 + lrow;
#pragma unroll
            for (int r = 0; r < 4; ++r) {
                int row = m0 + i * 16 + (lane >> 4) * 4 + r;
                float v = elu(acc[i][j][r] + bv2[j]);
                sv[j] += v;
                qv[j] += v * v;
                out[(size_t)row * 256 + col] = f2bf(v);
            }
        }
    }
#pragma unroll
    for (int j = 0; j < 4; ++j) {
        float s = sv[j], q_ = qv[j];
        s += __shfl_xor(s, 16); q_ += __shfl_xor(q_, 16);
        s += __shfl_xor(s, 32); q_ += __shfl_xor(q_, 32);
        if ((lane >> 4) == 0) {
            int col = wn * 64 + j * 16 + lrow;
            atomicAdd(&stats[col], s);
            atomicAdd(&stats[256 + col], q_);
        }
    }
}

// ============================================================================
// head_fused — r15 skeleton + BN3 affine+relu fused into A staging (r5 STG=3
// verified pattern: load S2, apply inline scale/shift from sums3, relu, pack,
// ds_write to the exact slot the GLL would fill). Replaces norm_affine_relu.
// ============================================================================
__global__ __launch_bounds__(256) void head_fused(const u16* __restrict__ A,
                                                  const u16* __restrict__ PB1,
                                                  const float* __restrict__ bo1,
                                                  const float* __restrict__ wo2,
                                                  const float* __restrict__ bo2,
                                                  const float* __restrict__ sums,
                                                  const float* __restrict__ g3,
                                                  const float* __restrict__ be3,
                                                  float* __restrict__ out) {
    __shared__ u16 As[2][64 * 32];
    __shared__ u16 Bs[2][256 * 32];
    __shared__ float rs[64 * 4];

    const int tid = threadIdx.x;
    const int lane = tid & 63, wid = tid >> 6;
    int bid = blockIdx.x;
    int bm = (bid & 7) * 40 + (bid >> 3);
    const int m0 = bm * 64;
    const int wn = wid;

    const size_t ab = (size_t)(m0 + (tid >> 2)) * 256 + (tid & 3) * 8;

    const int lrow = lane & 15;
    const int lk8 = (lane >> 4) * 8;

    f32x4 acc[4][4];
#pragma unroll
    for (int i = 0; i < 4; ++i)
#pragma unroll
        for (int j = 0; j < 4; ++j) acc[i][j] = (f32x4)0.f;

    auto stage1 = [&](int bf, int k0) {
        // register-staged A: BN3 affine + relu applied inline (r5 STG=3)
        u16x8 vin = *(const u16x8*)(A + ab + k0);
        u16x8 pk;
#pragma unroll
        for (int e = 0; e < 8; ++e) {
            int c = k0 + (tid & 3) * 8 + e;
            float mu = sums[c] * INV_R1;
            float var = sums[256 + c] * INV_R1 - mu * mu;
            float sc = g3[c] * rsqrtf(var + 1e-5f);
            float sh = be3[c] - mu * sc;
            float f = bf2f(vin[e]) * sc + sh;
            pk[e] = f2bf(f > 0.f ? f : 0.f);
        }
        *(u16x8*)&As[bf][tid * 8] = pk;
        const u16* b_ = PB1 + (size_t)(k0 >> 5) * 8192;
#pragma unroll
        for (int q = 0; q < 4; ++q)
            GLL(b_ + (q * 256 + tid) * 8, &Bs[bf][(q * 256 + tid) * 8]);
    };

    stage1(0, 0);
    __syncthreads();
    for (int kt = 0; kt < 8; ++kt) {
        if (kt + 1 < 8) stage1((kt + 1) & 1, (kt + 1) * 32);
        const int buf = kt & 1;
        bf16x8 a[4], b[4];
#pragma unroll
        for (int i = 0; i < 4; ++i)
            a[i] = *(const bf16x8*)&As[buf][(i * 16 + lrow) * 32 + lk8];
#pragma unroll
        for (int j = 0; j < 4; ++j)
            b[j] = *(const bf16x8*)&Bs[buf][(wn * 64 + j * 16 + lrow) * 32 + lk8];
#pragma unroll
        for (int i = 0; i < 4; ++i)
#pragma unroll
            for (int j = 0; j < 4; ++j)
                acc[i][j] = __builtin_amdgcn_mfma_f32_16x16x32_bf16(a[i], b[j], acc[i][j], 0, 0, 0);
        __syncthreads();
    }

    float p[4][4];
#pragma unroll
    for (int i = 0; i < 4; ++i)
#pragma unroll
        for (int r = 0; r < 4; ++r) p[i][r] = 0.f;
#pragma unroll
    for (int j = 0; j < 4; ++j) {
        int col = wn * 64 + j * 16 + lrow;
        float bv = bo1[col];
        float w = wo2[col];
#pragma unroll
        for (int i = 0; i < 4; ++i) {
#pragma unroll
            for (int r = 0; r < 4; ++r) {
                float v = acc[i][j][r] + bv;
                v = v > 0.f ? v : 0.f;
                p[i][r] += v * w;
            }
        }
    }
#pragma unroll
    for (int i = 0; i < 4; ++i) {
#pragma unroll
        for (int r = 0; r < 4; ++r) {
            float s = p[i][r];
            s += __shfl_xor(s, 1);
            s += __shfl_xor(s, 2);
            s += __shfl_xor(s, 4);
            s += __shfl_xor(s, 8);
            p[i][r] = s;
        }
    }
    if (lrow == 0) {
#pragma unroll
        for (int i = 0; i < 4; ++i)
#pragma unroll
            for (int r = 0; r < 4; ++r) {
                int rowlocal = i * 16 + (lane >> 4) * 4 + r;
                rs[rowlocal * 4 + wn] = p[i][r];
            }
    }
    __syncthreads();
    if (tid < 64) {
        float s = rs[tid * 4] + rs[tid * 4 + 1] + rs[tid * 4 + 2] + rs[tid * 4 + 3] + bo2[0];
        int m = m0 + tid;
        int b = m / (NV * TT);
        int v = (m >> 6) % NV;
        int t = m & 63;
        out[(size_t)(b * TT + t) * NV + v] = s;
    }
}

// -------------------- edge2node: incidence sum + BN2 affine (inline scsh) ----
__global__ __launch_bounds__(256) void edge2node(const u16* __restrict__ h2,
                                                 const float* __restrict__ sums,
                                                 const float* __restrict__ g2,
                                                 const float* __restrict__ be2,
                                                 u16* __restrict__ n1) {
    int tid = threadIdx.x;
    int row = blockIdx.x * 8 + (tid >> 5);
    int ch8 = (tid & 31) * 8;
    int t = row & 63;
    int bv = row >> 6;
    int v = bv % NV;
    int b = bv / NV;
    float acc[8] = {0, 0, 0, 0, 0, 0, 0, 0};
#pragma unroll
    for (int i = 0; i < 9; ++i) {
        int s = i + (i >= v ? 1 : 0);
        int e = s * 9 + (v < s ? v : v - 1);
        u16x8 vv = *(const u16x8*)(h2 + ((size_t)((b * NE + e) * TT + t)) * 256 + ch8);
#pragma unroll
        for (int k = 0; k < 8; ++k) acc[k] += bf2f(vv[k]);
    }
    const float inv9 = 1.f / 9.f;
    u16x8 o;
#pragma unroll
    for (int k = 0; k < 8; ++k) {
        int c = ch8 + k;
        float mu = sums[c] * INV_R2;
        float var = sums[256 + c] * INV_R2 - mu * mu;
        float sc = g2[c] * rsqrtf(var + 1e-5f);
        float sh = be2[c] - mu * sc;
        o[k] = f2bf(sc * (acc[k] * inv9) + sh);
    }
    *(u16x8*)(n1 + (size_t)row * 256 + ch8) = o;
}

extern "C" void kernel_launch(void* const* d_in, const int* in_sizes, int n_in,
                              void* d_out, int out_size, void* d_ws, size_t ws_size,
                              hipStream_t stream) {
    const float* x   = (const float*)d_in[0];
    const float* w1a = (const float*)d_in[1];
    const float* b1a = (const float*)d_in[2];
    const float* w1b = (const float*)d_in[3];
    const float* b1b = (const float*)d_in[4];
    const float* g1  = (const float*)d_in[5];
    const float* be1 = (const float*)d_in[6];
    const float* w2a = (const float*)d_in[7];
    const float* b2a = (const float*)d_in[8];
    const float* w2b = (const float*)d_in[9];
    const float* b2b = (const float*)d_in[10];
    const float* g2  = (const float*)d_in[11];
    const float* be2 = (const float*)d_in[12];
    const float* w3a = (const float*)d_in[13];
    const float* b3a = (const float*)d_in[14];
    const float* w3b = (const float*)d_in[15];
    const float* b3b = (const float*)d_in[16];
    const float* g3  = (const float*)d_in[17];
    const float* be3 = (const float*)d_in[18];
    const float* wo1 = (const float*)d_in[19];
    const float* bo1 = (const float*)d_in[20];
    const float* wo2 = (const float*)d_in[21];
    const float* bo2 = (const float*)d_in[22];
    float* out = (float*)d_out;

    char* ws = (char*)d_ws;
    size_t off = 0;
    auto alloc = [&](size_t bytes) {
        void* p = ws + off;
        off = (off + bytes + 255) & ~(size_t)255;
        return p;
    };
    u16* w1bP = (u16*)alloc(2 * 8 * 4096 * 2);
    u16* w3aP = (u16*)alloc(8 * 8192 * 2);
    u16* w3bP = (u16*)alloc(8 * 8192 * 2);
    u16* wo1P = (u16*)alloc(8 * 8192 * 2);
    u16* w2aP = (u16*)alloc(16 * 8192 * 2);
    u16* w2bP = (u16*)alloc(8 * 8192 * 2);
    float* sums  = (float*)alloc(3 * 512 * 4);
    float* b2aF  = (float*)alloc(256 * 4);
    u16* S0 = (u16*)alloc((size_t)R1 * 256 * 2);
    u16* S1 = (u16*)alloc((size_t)R1 * 256 * 2);
    u16* S2 = (u16*)alloc((size_t)R1 * 256 * 2);
    u16* BIG2 = (u16*)alloc((size_t)R2 * 256 * 2);

    pack128<<<16, 256, 0, stream>>>(w1b, w1bP);
    dim3 p3grid(8, 3);
    pack256_3<<<p3grid, 256, 0, stream>>>(w3a, w3aP, w3b, w3bP, wo1, wo1P);
    pack256s<<<8, 256, 0, stream>>>(w2b, w2bP);
    zero_stats<<<6, 256, 0, stream>>>(sums, 3 * 512);

    // mlp1: fc1 (VALU) + fc2 GEMM with fused stats
    mlp1_fc1<<<R1 / 8, 256, 0, stream>>>(x, w1a, b1a, S0);
    gemm_kernel<1, true><<<(R1 / 128) * 2, 256, 0, stream>>>(S0, w1bP, b1b, S1, 256, sums);
    pack256s_w2a<<<16, 256, 0, stream>>>(w2a, sums, g1, w2aP);
    fold_b2a<<<256, 256, 0, stream>>>(w2a, sums, g1, be1, b2a, b2aF);

    // mlp2: fused gather-fc1 + fc2 (padded-H1 engine)
    mlp2_fused<<<R2 / 128, 512, 0, stream>>>(S1, w2aP, b2aF, w2bP, b2b, BIG2, sums + 512);

    // edge2node (BN2 affine computed inline from sums)
    edge2node<<<R1 / 8, 256, 0, stream>>>(BIG2, sums + 512, g2, be2, S0);

    // mlp3: fused fc1+fc2 (padded H1), stats fused
    mlp3_fused<<<R1 / 64, 256, 0, stream>>>(S0, w3aP, b3a, w3bP, b3b, S2, sums + 1024);

    // head: BN3 affine+relu fused into staging; wo1 GEMM + dot wo2
    head_fused<<<R1 / 64, 256, 0, stream>>>(S2, wo1P, bo1, wo2, bo2,
                                            sums + 1024, g3, be3, out);
}